// Round 10
// baseline (12779.320 us; speedup 1.0000x reference)
//
#include <hip/hip_runtime.h>
#include <cstdint>

typedef __bf16 bf16;
typedef __bf16 bf16x8 __attribute__((ext_vector_type(8)));
typedef __bf16 bf16x4 __attribute__((ext_vector_type(4)));
typedef float f32x4 __attribute__((ext_vector_type(4)));

#define DI __device__ __forceinline__

#define BATCH 2048
#define HD 512
#define NM 6

DI float sigmoidf_(float x){ return 1.0f / (1.0f + __expf(-x)); }
DI float tanhf_(float x){
  float a = __expf(-2.0f * fabsf(x));
  float t = (1.0f - a) / (1.0f + a);
  return __builtin_copysignf(t, x);
}

// async global->LDS, 16B per lane; LDS dest = wave-uniform base + lane*16
DI void gload16(const bf16* g, char* l){
  __builtin_amdgcn_global_load_lds(
    (const __attribute__((address_space(1))) void*)g,
    (__attribute__((address_space(3))) void*)l, 16, 0, 0);
}

// diagnostic: encode ws_size into d_out[0] if workspace is too small
__global__ void k_diag(float* out, float wsmb){
  if (threadIdx.x == 0 && blockIdx.x == 0) out[0] = wsmb * 1.0e6f;
}

// ---------------------------------------------------------------------------
// Weight pack (fp32->bf16, optional gate-pack / dual-source K-concat)
// packed col p: nb=p>>7, hi=(p>>6)&1, g=(p>>4)&3, jl=p&15 -> row g*512+nb*32+hi*16+jl
// ---------------------------------------------------------------------------
template<bool GATES, bool DUAL>
__global__ void k_pack(bf16* __restrict__ dst, const float* __restrict__ s1,
                       const float* __restrict__ s2, int K, int NROW, int ksplit)
{
  long idx = (long)blockIdx.x * 256 + threadIdx.x;
  int kper = K >> 3;
  int k0 = (int)(idx % kper) * 8;
  long rest = idx / kper;
  int p = (int)(rest % NROW);
  int mm = (int)(rest / NROW);
  int r;
  if (GATES){
    int nb2 = p >> 7, hi = (p >> 6) & 1, g = (p >> 4) & 3, jl = p & 15;
    r = g * 512 + nb2 * 32 + hi * 16 + jl;
  } else r = p;
  const float* src;
  if (DUAL){
    if (k0 >= ksplit) src = s2 + ((long)mm * NROW + r) * ksplit + (k0 - ksplit);
    else              src = s1 + ((long)mm * NROW + r) * ksplit + k0;
  } else {
    src = s1 + ((long)mm * NROW + r) * K + k0;
  }
  f32x4 v0 = *(const f32x4*)(src);
  f32x4 v1 = *(const f32x4*)(src + 4);
  bf16x8 o;
  #pragma unroll
  for (int k = 0; k < 4; ++k){ o[k] = (bf16)v0[k]; o[4+k] = (bf16)v1[k]; }
  *(bf16x8*)(dst + ((long)mm * NROW + p) * K + k0) = o;
}

// time embeddings, pre-scaled by 0.5, rows 80..127 zero-padded
__global__ void k_temb(bf16* tembb, const float* tpW1, const float* tpb1,
                       const float* tpW2, const float* tpb2)
{
  int t = blockIdx.x; int tid = threadIdx.x;
  __shared__ float rq[256];
  float tn = (t < 80) ? (float)t / 79.0f : 0.0f;
  rq[tid] = fmaxf(tn * tpW1[tid] + tpb1[tid], 0.0f);
  __syncthreads();
  for (int d = tid; d < 512; d += 256){
    float s = tpb2[d];
    const float* w = tpW2 + d * 256;
    for (int q = 0; q < 256; ++q) s += rq[q] * w[q];
    tembb[t * 512 + d] = (bf16)((t < 80) ? 0.5f * s : 0.0f);
  }
}

// bias0p = b0i + b0h + 0.3 * fb_b @ W0i[:, :256].T (packed); bias1p = b1i + b1h (packed)
__global__ void k_biases(float* bias0p, float* bias1p,
                         const float* l0bih, const float* l0bhh,
                         const float* l1bih, const float* l1bhh,
                         const float* l0Wih, const float* fbb)
{
  int idx = blockIdx.x * 256 + threadIdx.x; // 6*2048
  int m = idx >> 11, p = idx & 2047;
  int nb2 = p >> 7, hi = (p >> 6) & 1, g = (p >> 4) & 3, jl = p & 15;
  int r = g * 512 + nb2 * 32 + hi * 16 + jl;
  bias1p[idx] = l1bih[m * 2048 + r] + l1bhh[m * 2048 + r];
  const float* wrow = l0Wih + ((long)m * 2048 + r) * 512;
  const float* fb = fbb + m * 256;
  float acc = 0.0f;
  for (int q = 0; q < 256; ++q) acc += fb[q] * wrow[q];
  bias0p[idx] = l0bih[m * 2048 + r] + l0bhh[m * 2048 + r] + 0.3f * acc;
}

// Feffp[m][o][p] = 0.3 * sum_q fb_W[m][q][o] * W0i[orig(p)][q]
__global__ void k_feffp(float* feffp, const float* fbW, const float* l0Wih)
{
  int idx = blockIdx.x * 256 + threadIdx.x; // 6*2*2048
  int p = idx & 2047, o = (idx >> 11) & 1, m = idx >> 12;
  int nb2 = p >> 7, hi = (p >> 6) & 1, g = (p >> 4) & 3, jl = p & 15;
  int r = g * 512 + nb2 * 32 + hi * 16 + jl;
  const float* wrow = l0Wih + ((long)m * 2048 + r) * 512;
  float acc = 0.0f;
  for (int q = 0; q < 256; ++q) acc += fbW[((long)m * 256 + q) * 2 + o] * wrow[q];
  feffp[((long)m * 2 + o) * 2048 + p] = 0.3f * acc;
}

// zero part buffer and trajectory[:, :, 0, :]
__global__ void k_zero(float* part, float* traj)
{
  int i = blockIdx.x * 256 + threadIdx.x; // 98304
  part[i] = 0.0f;
  if (i < 24576){
    int od = i & 1, mm = (i >> 1) % 6, b = i / 12;
    traj[b * 960 + mm * 160 + od] = 0.0f;
  }
}

// logits = lt1 @ cf_W2.T + cf_b2 ; confidences = softmax(logits/1.2)
__global__ void k_logits(const bf16* lt1, const float* cfW2, const float* cfb2,
                         float* conf, float* logitsOut)
{
  int b = blockIdx.x * 256 + threadIdx.x; // 2048
  float acc[6];
  #pragma unroll
  for (int mm = 0; mm < 6; ++mm) acc[mm] = cfb2[mm];
  for (int q = 0; q < 256; ++q){
    float xv = (float)lt1[b * 256 + q];
    #pragma unroll
    for (int mm = 0; mm < 6; ++mm) acc[mm] += xv * cfW2[mm * 256 + q];
  }
  float mx = acc[0];
  #pragma unroll
  for (int mm = 1; mm < 6; ++mm) mx = fmaxf(mx, acc[mm]);
  float e[6], s = 0.0f;
  #pragma unroll
  for (int mm = 0; mm < 6; ++mm){ e[mm] = __expf((acc[mm] - mx) * (1.0f / 1.2f)); s += e[mm]; }
  float inv = 1.0f / s;
  #pragma unroll
  for (int mm = 0; mm < 6; ++mm){
    logitsOut[b * 6 + mm] = acc[mm];
    conf[b * 6 + mm] = e[mm] * inv;
  }
}

// final: traj[79] = sum(part) + opb2
__global__ void k_red(const float* part, const float* opb2, float* traj)
{
  int i = blockIdx.x * 256 + threadIdx.x; // 12288
  int m = i >> 11, b = i & 2047;
  const float* pp = part + (long)i * 8;
  float o0 = pp[0] + pp[2] + pp[4] + pp[6] + opb2[m * 2];
  float o1 = pp[1] + pp[3] + pp[5] + pp[7] + opb2[m * 2 + 1];
  traj[(long)b * 960 + m * 160 + 158] = o0;
  traj[(long)b * 960 + m * 160 + 159] = o1;
}

struct GArgs {
  const bf16* A1; const bf16* A2; const bf16* Bw;
  long a1_ms, a2_ms, b_ms;
  int a_ld, K, ksplit, NBt, MBt, tprev;
  const float* biasf; long bias_ms;
  bf16* out_bf; long out_ms; int out_ld;
  float* out_f; long outf_ms;
  const bf16* baseb; long baseb_ms;
  const float* temb; long temb_ms;
  const float* feff; long feff_ms;
  const float* prevp;       // part buffer (read) [m][b][4][2]
  const float* ob2;         // opb2 [m][2]
  const float* w2;          // opW2 [m][2][512]
  float* part;              // part buffer (write, EP_OUT)
  float* cbuf; long c_ms;   // TRANSPOSED: [m][jh][b]
  bf16* hout; long h_ms;
  bf16* hout2; float* cbuf2;
};

enum { EP_RELU = 0, EP_BF16 = 1, EP_F32 = 2, EP_INIT = 3, EP_LSTM = 4, EP_OUT = 5, EP_BASE = 6 };

// ---------------------------------------------------------------------------
// gemm_w: 256x128 tile, 8 waves (512 thr), BK=64, double-buffered 96KB LDS,
// counted vmcnt(6), raw s_barriers, XOR-swizzled async staging, setprio MFMA.
// EP_LSTM register-direct epilogue only. 1 block/CU, grid = exact 3 rounds.
// ---------------------------------------------------------------------------
template<bool SPLIT, bool FB>
__global__ __launch_bounds__(512, 2)
void gemm_w(GArgs a)
{
  __shared__ __attribute__((aligned(16))) char smem[98304]; // 2 x (32KB A + 16KB B)

  const int id  = blockIdx.x;
  const int id2 = (id & 7) * ((int)gridDim.x >> 3) + (id >> 3);
  const int per = a.MBt * a.NBt;
  const int m   = id2 / per;
  const int rem = id2 - m * per;
  const int mb  = rem / a.NBt;
  const int nb  = rem - mb * a.NBt;

  const int tid = threadIdx.x;
  const int lane = tid & 63;
  const int wid  = tid >> 6;      // 0..7
  const int wr = wid >> 1;        // 0..3 (M band of 64)
  const int wc = wid & 1;         // 0..1 (N band of 64)

  const bf16* A1m = a.A1 + (long)m * a.a1_ms;
  const bf16* A2m = SPLIT ? (a.A2 + (long)m * a.a2_ms) : nullptr;
  const bf16* Bm  = a.Bw + (long)m * a.b_ms + (long)nb * 128 * a.K;

  f32x4 acc[4][4];
  #pragma unroll
  for (int i = 0; i < 4; ++i)
    #pragma unroll
    for (int j = 0; j < 4; ++j) acc[i][j] = f32x4{0.f, 0.f, 0.f, 0.f};

  // staging: A 256x64 (32KB) = 4 insts/thread; B 128x64 (16KB) = 2 insts.
  // XOR swizzle on global seg: sg = (lane&7)^(lane>>3); LDS linear.
  const int rl = lane >> 3;
  const int sg = (lane & 7) ^ rl;
  const bf16* a1B[4]; const bf16* a2B[4]; const bf16* bB[2];
  char* ldA[4]; char* ldB[2];
  #pragma unroll
  for (int c = 0; c < 4; ++c){
    int u  = wid * 4 + c;          // 0..31
    int rt = u * 8 + rl;           // 0..255
    a1B[c] = A1m + (long)(mb * 256 + rt) * a.a_ld + sg * 8;
    if (SPLIT) a2B[c] = A2m + (long)(mb * 256 + rt) * a.a_ld + sg * 8;
    ldA[c] = smem + u * 1024;
  }
  #pragma unroll
  for (int c = 0; c < 2; ++c){
    int u  = wid * 2 + c;          // 0..15
    int rt = u * 8 + rl;           // 0..127
    bB[c]  = Bm + (long)rt * a.K + sg * 8;
    ldB[c] = smem + 32768 + u * 1024;
  }
  auto STAGE = [&](int kb, int buf){
    int kcol = kb << 6;
    int off = buf * 49152;
    if (SPLIT && kcol >= a.ksplit){
      int kl = kcol - a.ksplit;
      #pragma unroll
      for (int c = 0; c < 4; ++c) gload16(a2B[c] + kl, ldA[c] + off);
      #pragma unroll
      for (int c = 0; c < 2; ++c) gload16(bB[c] + kcol, ldB[c] + off);
    } else {
      #pragma unroll
      for (int c = 0; c < 4; ++c) gload16(a1B[c] + kcol, ldA[c] + off);
      #pragma unroll
      for (int c = 0; c < 2; ++c) gload16(bB[c] + kcol, ldB[c] + off);
    }
  };

  const int nk = a.K >> 6;
  STAGE(0, 0);
  STAGE(1, 1);
  int cur = 0;
  for (int kb = 0; kb < nk; ++kb){
    // tile kb landed (outstanding <= STAGE(kb+1)'s 6 loads)
    if (kb + 1 < nk) asm volatile("s_waitcnt vmcnt(6)" ::: "memory");
    else             asm volatile("s_waitcnt vmcnt(0)" ::: "memory");
    __builtin_amdgcn_s_barrier();

    bf16x8 af[2][4], bg[2][4];
    const char* Asc = smem + cur * 49152;
    const char* Bsc = Asc + 32768;
    #pragma unroll
    for (int ks = 0; ks < 2; ++ks){
      const int kB = ks * 64 + ((lane >> 4) << 4);
      #pragma unroll
      for (int f = 0; f < 4; ++f){
        int rr = wr * 64 + f * 16 + (lane & 15);
        af[ks][f] = *(const bf16x8*)(Asc + rr * 128 + (kB ^ ((rr & 7) << 4)));
        int rb = wc * 64 + f * 16 + (lane & 15);
        bg[ks][f] = *(const bf16x8*)(Bsc + rb * 128 + (kB ^ ((rb & 7) << 4)));
      }
    }
    asm volatile("s_waitcnt lgkmcnt(0)" ::: "memory");
    __builtin_amdgcn_sched_barrier(0);
    __builtin_amdgcn_s_barrier();          // all waves done reading buf[cur]
    if (kb + 2 < nk) STAGE(kb + 2, cur);   // refill just-freed buffer

    __builtin_amdgcn_s_setprio(1);
    #pragma unroll
    for (int ks = 0; ks < 2; ++ks)
      #pragma unroll
      for (int i = 0; i < 4; ++i)
        #pragma unroll
        for (int j = 0; j < 4; ++j)
          acc[i][j] = __builtin_amdgcn_mfma_f32_16x16x32_bf16(af[ks][i], bg[ks][j], acc[i][j], 0, 0, 0);
    __builtin_amdgcn_s_setprio(0);
    cur ^= 1;
  }

  // ---- EP_LSTM register-direct (b = mb*256 + wr*64 + i*16 + qr*4 + q) ----
  {
    const int jl = lane & 15;
    const int qr = lane >> 4;
    const int jh = nb * 32 + wc * 16 + jl;
    const long pbase = (long)nb * 128 + wc * 64 + jl;
    float addv[4], f0v[4], f1v[4];
    #pragma unroll
    for (int g = 0; g < 4; ++g){
      long p = pbase + g * 16;
      if constexpr (FB){
        addv[g] = a.temb[(long)m * a.temb_ms + p];
        f0v[g]  = a.feff[(long)m * a.feff_ms + p];
        f1v[g]  = a.feff[(long)m * a.feff_ms + 2048 + p];
      } else {
        addv[g] = a.biasf[(long)m * a.bias_ms + p];
      }
    }
    const bf16* bb = FB ? (a.baseb + (long)m * a.baseb_ms + (long)nb * 2048 * 128
                           + wc * 64 + jl * 4) : nullptr;
    float* cb = a.cbuf + (long)m * a.c_ms + (long)jh * 2048;
    bf16*  hb = a.hout + (long)m * a.h_ms + jh;
    #pragma unroll
    for (int i = 0; i < 4; ++i){
      int b0 = mb * 256 + wr * 64 + i * 16 + qr * 4;
      f32x4 cv = *(f32x4*)(cb + b0);
      f32x4 cnv;
      #pragma unroll
      for (int q = 0; q < 4; ++q){
        int b = b0 + q;
        float pv0 = 0.f, pv1 = 0.f;
        bf16x4 bv4;
        if constexpr (FB){
          bv4 = *(const bf16x4*)(bb + (long)b * 128);
          if (a.tprev >= 0){
            const float* pp = a.prevp + ((long)m * 2048 + b) * 8;
            f32x4 pa = *(const f32x4*)(pp);
            f32x4 pb = *(const f32x4*)(pp + 4);
            pv0 = pa[0] + pa[2] + pb[0] + pb[2] + a.ob2[m * 2];
            pv1 = pa[1] + pa[3] + pb[1] + pb[3] + a.ob2[m * 2 + 1];
          }
          if (nb == 0 && wc == 0 && jl == 0 && a.tprev >= 1){
            a.out_f[(long)b * 960 + m * 160 + a.tprev * 2 + 0] = pv0;
            a.out_f[(long)b * 960 + m * 160 + a.tprev * 2 + 1] = pv1;
          }
        }
        float g4[4];
        #pragma unroll
        for (int g = 0; g < 4; ++g){
          float v = acc[i][g][q] + addv[g];
          if constexpr (FB){
            v += (float)bv4[g];
            v += pv0 * f0v[g] + pv1 * f1v[g];
          }
          g4[g] = v;
        }
        float ci = sigmoidf_(g4[0]), cf = sigmoidf_(g4[1]);
        float cg = tanhf_(g4[2]),    co = sigmoidf_(g4[3]);
        float cn = cf * cv[q] + ci * cg;
        cnv[q] = cn;
        hb[(long)b * HD] = (bf16)(co * tanhf_(cn));
      }
      *(f32x4*)(cb + b0) = cnv;
    }
  }
}

// ---------------------------------------------------------------------------
// gemm_k: 128x128 tile, BK=32, 4 waves — used for precompute + G3 (EP_OUT).
// ---------------------------------------------------------------------------
template<int EP, bool SPLIT, bool FB>
__global__ __launch_bounds__(256, 3)
void gemm_k(GArgs a)
{
  __shared__ __attribute__((aligned(16))) char smem[33792];
  char* As = smem;            // 128x32 bf16 = 8KB
  char* Bs = smem + 8192;     // 8KB
  float* Gf = (float*)smem;   // epilogue alias

  const int id  = blockIdx.x;
  const int id2 = (id & 7) * ((int)gridDim.x >> 3) + (id >> 3);
  const int per = a.MBt * a.NBt;
  const int m   = id2 / per;
  const int rem = id2 - m * per;
  const int mb  = rem / a.NBt;
  const int nb  = rem - mb * a.NBt;

  const int tid = threadIdx.x;
  const int lane = tid & 63;
  const int wid  = tid >> 6;
  const int wr = wid >> 1, wc = wid & 1;

  const bf16* A1m = a.A1 + (long)m * a.a1_ms;
  const bf16* A2m = SPLIT ? (a.A2 + (long)m * a.a2_ms) : nullptr;
  const bf16* Bm  = a.Bw + (long)m * a.b_ms + (long)nb * 128 * a.K;

  f32x4 acc[4][4];
  #pragma unroll
  for (int i = 0; i < 4; ++i)
    #pragma unroll
    for (int j = 0; j < 4; ++j) acc[i][j] = f32x4{0.f, 0.f, 0.f, 0.f};

  const int rl = lane >> 2;
  const int sg = lane & 3;
  const bf16* a1B[2]; const bf16* a2B[2]; const bf16* bB[2];
  char* ldA[2]; char* ldB[2];
  #pragma unroll
  for (int c = 0; c < 2; ++c){
    int u  = wid * 2 + c;
    int rt = u * 16 + rl;
    a1B[c] = A1m + (long)(mb * 128 + rt) * a.a_ld + sg * 8;
    if (SPLIT) a2B[c] = A2m + (long)(mb * 128 + rt) * a.a_ld + sg * 8;
    bB[c]  = Bm + (long)rt * a.K + sg * 8;
    ldA[c] = As + u * 1024;
    ldB[c] = Bs + u * 1024;
  }
  auto STAGE = [&](int kb){
    int kcol = kb << 5;
    if (SPLIT && kcol >= a.ksplit){
      int kl = kcol - a.ksplit;
      #pragma unroll
      for (int c = 0; c < 2; ++c){ gload16(a2B[c] + kl, ldA[c]); gload16(bB[c] + kcol, ldB[c]); }
    } else {
      #pragma unroll
      for (int c = 0; c < 2; ++c){ gload16(a1B[c] + kcol, ldA[c]); gload16(bB[c] + kcol, ldB[c]); }
    }
  };

  const int nk = a.K >> 5;
  STAGE(0);
  for (int kb = 0; kb < nk; ++kb){
    __syncthreads();
    bf16x8 af[4], bg[4];
    const int kB = (lane >> 4) << 4;
    #pragma unroll
    for (int f = 0; f < 4; ++f){
      int rr = wr * 64 + f * 16 + (lane & 15);
      af[f] = *(const bf16x8*)(As + rr * 64 + kB);
      int rb = wc * 64 + f * 16 + (lane & 15);
      bg[f] = *(const bf16x8*)(Bs + rb * 64 + kB);
    }
    __syncthreads();
    if (kb + 1 < nk) STAGE(kb + 1);
    #pragma unroll
    for (int i = 0; i < 4; ++i)
      #pragma unroll
      for (int j = 0; j < 4; ++j)
        acc[i][j] = __builtin_amdgcn_mfma_f32_16x16x32_bf16(af[i], bg[j], acc[i][j], 0, 0, 0);
  }

  // ---- EP_BASE: write gates+bias0 in epilogue layout [m][nb][b][wc][jl][g]
  if constexpr (EP == EP_BASE){
    const int jl = lane & 15;
    const int qr = lane >> 4;
    const long pbase = (long)nb * 128 + wc * 64 + jl;
    float addv[4];
    #pragma unroll
    for (int g = 0; g < 4; ++g) addv[g] = a.biasf[(long)m * a.bias_ms + pbase + g * 16];
    bf16* dst = a.out_bf + (long)m * a.out_ms + (long)nb * 2048 * 128 + wc * 64 + jl * 4;
    #pragma unroll
    for (int i = 0; i < 4; ++i){
      #pragma unroll
      for (int q = 0; q < 4; ++q){
        int b = mb * 128 + wr * 64 + i * 16 + qr * 4 + q;
        bf16x4 ov;
        #pragma unroll
        for (int g = 0; g < 4; ++g) ov[g] = (bf16)(acc[i][g][q] + addv[g]);
        *(bf16x4*)(dst + (long)b * 128) = ov;
      }
    }
    return;
  }

  // ---- EP_OUT: fused out-projection, straight from registers ----
  if constexpr (EP == EP_OUT){
    __syncthreads();
    float* ps = (float*)smem;   // [128][4]
    int colbase = wc * 64 + (lane & 15);
    float bv[4], w0v[4], w1v[4];
    #pragma unroll
    for (int j = 0; j < 4; ++j){
      int p = nb * 128 + colbase + j * 16;
      bv[j]  = a.biasf[(long)m * a.bias_ms + p];
      w0v[j] = a.w2[(long)m * 1024 + p];
      w1v[j] = a.w2[(long)m * 1024 + 512 + p];
    }
    #pragma unroll
    for (int i = 0; i < 4; ++i)
      #pragma unroll
      for (int q = 0; q < 4; ++q){
        float s0 = 0.f, s1 = 0.f;
        #pragma unroll
        for (int j = 0; j < 4; ++j){
          float v = fmaxf(acc[i][j][q] + bv[j], 0.0f);
          s0 += v * w0v[j]; s1 += v * w1v[j];
        }
        #pragma unroll
        for (int o2 = 1; o2 < 16; o2 <<= 1){ s0 += __shfl_xor(s0, o2); s1 += __shfl_xor(s1, o2); }
        if ((lane & 15) == 0){
          int row = wr * 64 + i * 16 + ((lane >> 4) << 2) + q;
          ps[row * 4 + wc * 2 + 0] = s0;
          ps[row * 4 + wc * 2 + 1] = s1;
        }
      }
    __syncthreads();
    if (tid < 128){
      int b = mb * 128 + tid;
      float o0 = ps[tid * 4 + 0] + ps[tid * 4 + 2];
      float o1 = ps[tid * 4 + 1] + ps[tid * 4 + 3];
      a.part[((long)m * 2048 + b) * 8 + nb * 2 + 0] = o0;
      a.part[((long)m * 2048 + b) * 8 + nb * 2 + 1] = o1;
    }
    return;
  }

  // ---- generic epilogues via LDS G tile, two 64-col passes (precompute only)
  #pragma unroll 1
  for (int ph = 0; ph < 2; ++ph){
    __syncthreads();
    if (wc == ph){
      #pragma unroll
      for (int i = 0; i < 4; ++i)
        #pragma unroll
        for (int j = 0; j < 4; ++j)
          #pragma unroll
          for (int q = 0; q < 4; ++q){
            int rr = wr * 64 + i * 16 + ((lane >> 4) << 2) + q;
            int cc = j * 16 + (lane & 15);
            Gf[rr * 66 + cc] = acc[i][j][q];
          }
    }
    __syncthreads();

    #pragma unroll 1
    for (int it = 0; it < 4; ++it){
      int u = it * 256 + tid;
      int r = u >> 3, cg = u & 7;
      int b = mb * 128 + r;
      int p0 = nb * 128 + ph * 64 + cg * 8;
      float v[8];
      #pragma unroll
      for (int k2 = 0; k2 < 8; ++k2){
        v[k2] = Gf[r * 66 + cg * 8 + k2];
        if (a.biasf) v[k2] += a.biasf[(long)m * a.bias_ms + p0 + k2];
        if constexpr (EP == EP_RELU) v[k2] = fmaxf(v[k2], 0.0f);
      }
      if constexpr (EP == EP_F32){
        float* dst = a.out_f + (long)m * a.outf_ms + (long)b * a.out_ld + p0;
        #pragma unroll
        for (int k2 = 0; k2 < 8; ++k2) dst[k2] = v[k2];
      } else if constexpr (EP == EP_INIT){
        if (p0 < HD){
          bf16x8 ov;
          #pragma unroll
          for (int k2 = 0; k2 < 8; ++k2) ov[k2] = (bf16)v[k2];
          *(bf16x8*)(a.hout  + (long)m * a.h_ms + (long)b * HD + p0) = ov;
          *(bf16x8*)(a.hout2 + (long)m * a.h_ms + (long)b * HD + p0) = ov;
        } else {
          int p1 = p0 - HD;
          // transposed c layout: [m][jh][b]
          #pragma unroll
          for (int k2 = 0; k2 < 8; ++k2){
            a.cbuf [(long)m * a.c_ms + (long)(p1 + k2) * 2048 + b] = v[k2];
            a.cbuf2[(long)m * a.c_ms + (long)(p1 + k2) * 2048 + b] = v[k2];
          }
        }
      } else {
        bf16x8 ov;
        #pragma unroll
        for (int k2 = 0; k2 < 8; ++k2) ov[k2] = (bf16)v[k2];
        *(bf16x8*)(a.out_bf + (long)m * a.out_ms + (long)b * a.out_ld + p0) = ov;
      }
    }
  }
}

// ---------------------------------------------------------------------------
extern "C" void kernel_launch(void* const* d_in, const int* in_sizes, int n_in,
                              void* d_out, int out_size, void* d_ws, size_t ws_size,
                              hipStream_t stream)
{
  (void)in_sizes; (void)n_in; (void)out_size;
  const float* X     = (const float*)d_in[0];
  const float* mdW1  = (const float*)d_in[1];
  const float* mdb1  = (const float*)d_in[2];
  const float* mdW2  = (const float*)d_in[3];
  const float* mdb2  = (const float*)d_in[4];
  const float* mdW3  = (const float*)d_in[5];
  const float* mdb3  = (const float*)d_in[6];
  const float* ihW   = (const float*)d_in[7];
  const float* ihb   = (const float*)d_in[8];
  const float* tpW1  = (const float*)d_in[9];
  const float* tpb1  = (const float*)d_in[10];
  const float* tpW2  = (const float*)d_in[11];
  const float* tpb2  = (const float*)d_in[12];
  const float* fbW   = (const float*)d_in[13];
  const float* fbb   = (const float*)d_in[14];
  const float* l0Wih = (const float*)d_in[15];
  const float* l0bih = (const float*)d_in[16];
  const float* l0Whh = (const float*)d_in[17];
  const float* l0bhh = (const float*)d_in[18];
  const float* l1Wih = (const float*)d_in[19];
  const float* l1bih = (const float*)d_in[20];
  const float* l1Whh = (const float*)d_in[21];
  const float* l1bhh = (const float*)d_in[22];
  const float* opW1  = (const float*)d_in[23];
  const float* opb1  = (const float*)d_in[24];
  const float* opW2  = (const float*)d_in[25];
  const float* opb2  = (const float*)d_in[26];
  const float* cfW1  = (const float*)d_in[27];
  const float* cfb1  = (const float*)d_in[28];
  const float* cfW2  = (const float*)d_in[29];
  const float* cfb2  = (const float*)d_in[30];
  float* out = (float*)d_out;

  // ---- static arena (liveness-aliased). Total = 211,009,536 B ----
  const size_t NEED = 211009536;
  if (ws_size < NEED){
    k_diag<<<1, 64, 0, stream>>>(out, (float)(ws_size >> 20));
    return;
  }
  char* ws = (char*)d_ws;
  const long BH = (long)BATCH * HD;

  // persistent (loop-live)
  bf16*  Wp0     = (bf16*) (ws + 0);           // 12,582,912
  bf16*  Wp1     = (bf16*) (ws + 12582912);    // 25,165,824
  bf16*  WpO     = (bf16*) (ws + 37748736);    //  3,145,728
  bf16*  base0r  = (bf16*) (ws + 40894464);    // 50,331,648 [m][nb][b][wc][jl][g]
  float* tembW0p = (float*)(ws + 91226112);    //  6,291,456
  float* bias1p  = (float*)(ws + 97517568);    //     49,152
  float* Feffp   = (float*)(ws + 97566720);    //     98,304
  char*  REG     =          ws + 97763328;     // 100,663,296 (h0|h1|c0|c1)
  bf16*  h0b     = (bf16*) (REG + 0);
  bf16*  h1b     = (bf16*) (REG + 25165824);
  float* c0      = (float*)(REG + 50331648);   // transposed [m][jh][b]
  float* c1      = (float*)(REG + 75497472);   // transposed [m][jh][b]
  char*  MREG    =          ws + 198426624;    // 12,582,912

  // precompute temporaries inside REG (dead before EP_INIT writes h/c)
  bf16*  W0ip    = (bf16*) (REG + 0);
  bf16*  mdW1p   = (bf16*) (REG + 12582912);
  bf16*  mdW2p   = (bf16*) (REG + 18874368);
  bf16*  mdW3p   = (bf16*) (REG + 25165824);
  bf16*  tembb   = (bf16*) (REG + 28311552);
  float* bias0p  = (float*)(REG + 28442624);
  bf16*  lt1     = (bf16*) (REG + 28491776);
  bf16*  t1buf   = (bf16*) (REG + 29540352);
  bf16*  t2buf   = (bf16*) (REG + 54706176);
  bf16*  mfbuf   = (bf16*) (REG + 67289088);
  // MREG: precompute temporaries + loop-live part buffer (disjoint)
  bf16*  xb      = (bf16*) (MREG + 0);         //  2,097,152
  bf16*  ihWp    = (bf16*) (MREG + 2097152);   //  6,291,456
  bf16*  cfW1p   = (bf16*) (MREG + 8388608);   //    262,144
  float* part    = (float*)(MREG + 8650752);   //    393,216  [m][b][4][2]

  // ---- pack / convert ----
  k_pack<false,false><<<dim3(512),  256, 0, stream>>>(xb,    X,     nullptr, 512,  2048, 512);
  k_pack<true ,false><<<dim3(3072), 256, 0, stream>>>(Wp0,   l0Whh, nullptr, 512,  2048, 512);
  k_pack<true ,false><<<dim3(3072), 256, 0, stream>>>(W0ip,  l0Wih, nullptr, 512,  2048, 512);
  k_pack<true ,true ><<<dim3(6144), 256, 0, stream>>>(Wp1,   l1Wih, l1Whh,   1024, 2048, 512);
  k_pack<false,false><<<dim3(768),  256, 0, stream>>>(WpO,   opW1,  nullptr, 512,  512,  512);
  k_pack<false,false><<<dim3(1536), 256, 0, stream>>>(mdW1p, mdW1,  nullptr, 512,  1024, 512);
  k_pack<false,false><<<dim3(1536), 256, 0, stream>>>(mdW2p, mdW2,  nullptr, 1024, 512,  1024);
  k_pack<false,false><<<dim3(768),  256, 0, stream>>>(mdW3p, mdW3,  nullptr, 512,  512,  512);
  k_pack<false,false><<<dim3(1536), 256, 0, stream>>>(ihWp,  ihW,   nullptr, 512,  1024, 512);
  k_pack<false,false><<<dim3(64),   256, 0, stream>>>(cfW1p, cfW1,  nullptr, 512,  256,  512);

  k_temb  <<<dim3(128), 256, 0, stream>>>(tembb, tpW1, tpb1, tpW2, tpb2);
  k_biases<<<dim3(48),  256, 0, stream>>>(bias0p, bias1p, l0bih, l0bhh, l1bih, l1bhh, l0Wih, fbb);
  k_feffp <<<dim3(96),  256, 0, stream>>>(Feffp, fbW, l0Wih);
  k_zero  <<<dim3(384), 256, 0, stream>>>(part, out);

  // ---- precompute GEMMs (order matters for arena aliasing) ----
  { GArgs g{}; g.A1 = xb; g.a1_ms = 0; g.a_ld = 512; g.Bw = mdW1p; g.b_ms = (long)1024*512;
    g.K = 512; g.ksplit = 512; g.NBt = 8; g.MBt = 16; g.biasf = mdb1; g.bias_ms = 1024;
    g.out_bf = t1buf; g.out_ms = (long)2048*1024; g.out_ld = 1024;
    gemm_k<EP_RELU,false,false><<<dim3(16*8*6), 256, 0, stream>>>(g); }
  { GArgs g{}; g.A1 = t1buf; g.a1_ms = (long)2048*1024; g.a_ld = 1024; g.Bw = mdW2p; g.b_ms = (long)512*1024;
    g.K = 1024; g.ksplit = 1024; g.NBt = 4; g.MBt = 16; g.biasf = mdb2; g.bias_ms = 512;
    g.out_bf = t2buf; g.out_ms = BH; g.out_ld = 512;
    gemm_k<EP_RELU,false,false><<<dim3(16*4*6), 256, 0, stream>>>(g); }
  { GArgs g{}; g.A1 = t2buf; g.a1_ms = BH; g.a_ld = 512; g.Bw = mdW3p; g.b_ms = (long)512*512;
    g.K = 512; g.ksplit = 512; g.NBt = 4; g.MBt = 16; g.biasf = mdb3; g.bias_ms = 512;
    g.out_bf = mfbuf; g.out_ms = BH; g.out_ld = 512;
    gemm_k<EP_BF16,false,false><<<dim3(16*4*6), 256, 0, stream>>>(g); }
  { GArgs g{}; g.A1 = tembb; g.a1_ms = 0; g.a_ld = 512; g.Bw = W0ip; g.b_ms = (long)2048*512;
    g.K = 512; g.ksplit = 512; g.NBt = 16; g.MBt = 1; g.biasf = nullptr;
    g.out_f = tembW0p; g.outf_ms = (long)128*2048; g.out_ld = 2048;
    gemm_k<EP_F32,false,false><<<dim3(1*16*6), 256, 0, stream>>>(g); }
  // base0 in epilogue-matched layout (EP_BASE), bias0p folded in
  { GArgs g{}; g.A1 = mfbuf; g.a1_ms = BH; g.a_ld = 512; g.Bw = W0ip; g.b_ms = (long)2048*512;
    g.K = 512; g.ksplit = 512; g.NBt = 16; g.MBt = 16; g.biasf = bias0p; g.bias_ms = 2048;
    g.out_bf = base0r; g.out_ms = (long)2048*2048;
    gemm_k<EP_BASE,false,false><<<dim3(16*16*6), 256, 0, stream>>>(g); }
  { GArgs g{}; g.A1 = xb; g.a1_ms = 0; g.a_ld = 512; g.Bw = cfW1p; g.b_ms = 0;
    g.K = 512; g.ksplit = 512; g.NBt = 2; g.MBt = 16; g.biasf = cfb1; g.bias_ms = 0;
    g.out_bf = lt1; g.out_ms = 0; g.out_ld = 256;
    gemm_k<EP_RELU,false,false><<<dim3(16*2*1), 256, 0, stream>>>(g); }
  k_logits<<<dim3(8), 256, 0, stream>>>(lt1, cfW2, cfb2, out + 1966080, out + 1966080 + 12288);
  { GArgs g{}; g.A1 = xb; g.a1_ms = 0; g.a_ld = 512; g.Bw = ihWp; g.b_ms = (long)1024*512;
    g.K = 512; g.ksplit = 512; g.NBt = 8; g.MBt = 16; g.biasf = ihb; g.bias_ms = 1024;
    g.hout = h0b; g.h_ms = BH; g.hout2 = h1b; g.cbuf = c0; g.c_ms = BH; g.cbuf2 = c1;
    gemm_k<EP_INIT,false,false><<<dim3(16*8*6), 256, 0, stream>>>(g); }

  // ---- recurrent loop (3 dispatches/step; G1/G2 on gemm_w 256x128) ----
  for (int t = 0; t < 80; ++t){
    int cur = t & 1, nxt = cur ^ 1;
    { GArgs g{}; g.A1 = h0b + (size_t)cur * 6 * BH; g.a1_ms = BH; g.a_ld = 512;
      g.Bw = Wp0; g.b_ms = (long)2048*512; g.K = 512; g.ksplit = 512; g.NBt = 16; g.MBt = 8;
      g.tprev = t - 1;
      g.baseb = base0r; g.baseb_ms = (long)2048*2048;
      g.temb = tembW0p + (long)t * 2048; g.temb_ms = (long)128*2048;
      g.feff = Feffp; g.feff_ms = 4096;
      g.prevp = part; g.ob2 = opb2; g.out_f = out;
      g.cbuf = c0; g.c_ms = BH;
      g.hout = h0b + (size_t)nxt * 6 * BH; g.h_ms = BH;
      gemm_w<false,true><<<dim3(8*16*6), 512, 0, stream>>>(g); }
    { GArgs g{}; g.A1 = h0b + (size_t)nxt * 6 * BH; g.A2 = h1b + (size_t)cur * 6 * BH;
      g.a1_ms = BH; g.a2_ms = BH; g.a_ld = 512;
      g.Bw = Wp1; g.b_ms = (long)2048*1024; g.K = 1024; g.ksplit = 512; g.NBt = 16; g.MBt = 8;
      g.biasf = bias1p; g.bias_ms = 2048;
      g.cbuf = c1; g.c_ms = BH;
      g.hout = h1b + (size_t)nxt * 6 * BH; g.h_ms = BH;
      gemm_w<true,false><<<dim3(8*16*6), 512, 0, stream>>>(g); }
    { GArgs g{}; g.A1 = h1b + (size_t)nxt * 6 * BH; g.a1_ms = BH; g.a_ld = 512;
      g.Bw = WpO; g.b_ms = (long)512*512; g.K = 512; g.ksplit = 512; g.NBt = 4; g.MBt = 16;
      g.biasf = opb1; g.bias_ms = 512;
      g.w2 = opW2; g.part = part;
      gemm_k<EP_OUT,false,false><<<dim3(16*4*6), 256, 0, stream>>>(g); }
  }
  k_red<<<dim3(48), 256, 0, stream>>>(part, opb2, out);
}

// Round 11
// 11290.578 us; speedup vs baseline: 1.1319x; 1.1319x over previous
//
#include <hip/hip_runtime.h>
#include <cstdint>

typedef __bf16 bf16;
typedef __bf16 bf16x8 __attribute__((ext_vector_type(8)));
typedef float f32x4 __attribute__((ext_vector_type(4)));

#define DI __device__ __forceinline__

#define BATCH 2048
#define HD 512
#define NM 6

DI float sigmoidf_(float x){ return 1.0f / (1.0f + __expf(-x)); }
DI float tanhf_(float x){
  float a = __expf(-2.0f * fabsf(x));
  float t = (1.0f - a) / (1.0f + a);
  return __builtin_copysignf(t, x);
}

// async global->LDS, 16B per lane; LDS dest = wave-uniform base + lane*16
DI void gload16(const bf16* g, char* l){
  __builtin_amdgcn_global_load_lds(
    (const __attribute__((address_space(1))) void*)g,
    (__attribute__((address_space(3))) void*)l, 16, 0, 0);
}

// diagnostic: encode ws_size into d_out[0] if workspace is too small
__global__ void k_diag(float* out, float wsmb){
  if (threadIdx.x == 0 && blockIdx.x == 0) out[0] = wsmb * 1.0e6f;
}

// ---------------------------------------------------------------------------
// Weight pack (fp32->bf16, optional gate-pack / dual-source K-concat)
// packed col p: nb=p>>7, hi=(p>>6)&1, g=(p>>4)&3, jl=p&15 -> row g*512+nb*32+hi*16+jl
// ---------------------------------------------------------------------------
template<bool GATES, bool DUAL>
__global__ void k_pack(bf16* __restrict__ dst, const float* __restrict__ s1,
                       const float* __restrict__ s2, int K, int NROW, int ksplit)
{
  long idx = (long)blockIdx.x * 256 + threadIdx.x;
  int kper = K >> 3;
  int k0 = (int)(idx % kper) * 8;
  long rest = idx / kper;
  int p = (int)(rest % NROW);
  int mm = (int)(rest / NROW);
  int r;
  if (GATES){
    int nb2 = p >> 7, hi = (p >> 6) & 1, g = (p >> 4) & 3, jl = p & 15;
    r = g * 512 + nb2 * 32 + hi * 16 + jl;
  } else r = p;
  const float* src;
  if (DUAL){
    if (k0 >= ksplit) src = s2 + ((long)mm * NROW + r) * ksplit + (k0 - ksplit);
    else              src = s1 + ((long)mm * NROW + r) * ksplit + k0;
  } else {
    src = s1 + ((long)mm * NROW + r) * K + k0;
  }
  f32x4 v0 = *(const f32x4*)(src);
  f32x4 v1 = *(const f32x4*)(src + 4);
  bf16x8 o;
  #pragma unroll
  for (int k = 0; k < 4; ++k){ o[k] = (bf16)v0[k]; o[4+k] = (bf16)v1[k]; }
  *(bf16x8*)(dst + ((long)mm * NROW + p) * K + k0) = o;
}

// time embeddings, pre-scaled by 0.5, rows 80..127 zero-padded
__global__ void k_temb(bf16* tembb, const float* tpW1, const float* tpb1,
                       const float* tpW2, const float* tpb2)
{
  int t = blockIdx.x; int tid = threadIdx.x;
  __shared__ float rq[256];
  float tn = (t < 80) ? (float)t / 79.0f : 0.0f;
  rq[tid] = fmaxf(tn * tpW1[tid] + tpb1[tid], 0.0f);
  __syncthreads();
  for (int d = tid; d < 512; d += 256){
    float s = tpb2[d];
    const float* w = tpW2 + d * 256;
    for (int q = 0; q < 256; ++q) s += rq[q] * w[q];
    tembb[t * 512 + d] = (bf16)((t < 80) ? 0.5f * s : 0.0f);
  }
}

// bias0p = b0i + b0h + 0.3 * fb_b @ W0i[:, :256].T (packed); bias1p = b1i + b1h (packed)
__global__ void k_biases(float* bias0p, float* bias1p,
                         const float* l0bih, const float* l0bhh,
                         const float* l1bih, const float* l1bhh,
                         const float* l0Wih, const float* fbb)
{
  int idx = blockIdx.x * 256 + threadIdx.x; // 6*2048
  int m = idx >> 11, p = idx & 2047;
  int nb2 = p >> 7, hi = (p >> 6) & 1, g = (p >> 4) & 3, jl = p & 15;
  int r = g * 512 + nb2 * 32 + hi * 16 + jl;
  bias1p[idx] = l1bih[m * 2048 + r] + l1bhh[m * 2048 + r];
  const float* wrow = l0Wih + ((long)m * 2048 + r) * 512;
  const float* fb = fbb + m * 256;
  float acc = 0.0f;
  for (int q = 0; q < 256; ++q) acc += fb[q] * wrow[q];
  bias0p[idx] = l0bih[m * 2048 + r] + l0bhh[m * 2048 + r] + 0.3f * acc;
}

// Feffp[m][o][p] = 0.3 * sum_q fb_W[m][q][o] * W0i[orig(p)][q]
__global__ void k_feffp(float* feffp, const float* fbW, const float* l0Wih)
{
  int idx = blockIdx.x * 256 + threadIdx.x; // 6*2*2048
  int p = idx & 2047, o = (idx >> 11) & 1, m = idx >> 12;
  int nb2 = p >> 7, hi = (p >> 6) & 1, g = (p >> 4) & 3, jl = p & 15;
  int r = g * 512 + nb2 * 32 + hi * 16 + jl;
  const float* wrow = l0Wih + ((long)m * 2048 + r) * 512;
  float acc = 0.0f;
  for (int q = 0; q < 256; ++q) acc += fbW[((long)m * 256 + q) * 2 + o] * wrow[q];
  feffp[((long)m * 2 + o) * 2048 + p] = 0.3f * acc;
}

// zero part buffer and trajectory[:, :, 0, :]
__global__ void k_zero(float* part, float* traj)
{
  int i = blockIdx.x * 256 + threadIdx.x; // 98304
  part[i] = 0.0f;
  if (i < 24576){
    int od = i & 1, mm = (i >> 1) % 6, b = i / 12;
    traj[b * 960 + mm * 160 + od] = 0.0f;
  }
}

// logits = lt1 @ cf_W2.T + cf_b2 ; confidences = softmax(logits/1.2)
__global__ void k_logits(const bf16* lt1, const float* cfW2, const float* cfb2,
                         float* conf, float* logitsOut)
{
  int b = blockIdx.x * 256 + threadIdx.x; // 2048
  float acc[6];
  #pragma unroll
  for (int mm = 0; mm < 6; ++mm) acc[mm] = cfb2[mm];
  for (int q = 0; q < 256; ++q){
    float xv = (float)lt1[b * 256 + q];
    #pragma unroll
    for (int mm = 0; mm < 6; ++mm) acc[mm] += xv * cfW2[mm * 256 + q];
  }
  float mx = acc[0];
  #pragma unroll
  for (int mm = 1; mm < 6; ++mm) mx = fmaxf(mx, acc[mm]);
  float e[6], s = 0.0f;
  #pragma unroll
  for (int mm = 0; mm < 6; ++mm){ e[mm] = __expf((acc[mm] - mx) * (1.0f / 1.2f)); s += e[mm]; }
  float inv = 1.0f / s;
  #pragma unroll
  for (int mm = 0; mm < 6; ++mm){
    logitsOut[b * 6 + mm] = acc[mm];
    conf[b * 6 + mm] = e[mm] * inv;
  }
}

// final: traj[79] = sum(part) + opb2
__global__ void k_red(const float* part, const float* opb2, float* traj)
{
  int i = blockIdx.x * 256 + threadIdx.x; // 12288
  int m = i >> 11, b = i & 2047;
  const float* pp = part + (long)i * 8;
  float o0 = pp[0] + pp[2] + pp[4] + pp[6] + opb2[m * 2];
  float o1 = pp[1] + pp[3] + pp[5] + pp[7] + opb2[m * 2 + 1];
  traj[(long)b * 960 + m * 160 + 158] = o0;
  traj[(long)b * 960 + m * 160 + 159] = o1;
}

// ---------------------------------------------------------------------------
// Main GEMM: C = A @ Bw.T, 128x128 tile, BK=64, 4 waves, 16x16x32 bf16 MFMA.
// Staging: async global_load_lds dwordx4, LDS linear per wave-op, XOR swizzle
// applied on the per-lane GLOBAL source segment (sg = (lane&7)^(lane>>3)) so
// the ds_read side's swizzled reads see the right data (m173 pattern).
// ---------------------------------------------------------------------------
struct GArgs {
  const bf16* A1; const bf16* A2; const bf16* Bw;
  long a1_ms, a2_ms, b_ms;
  int a_ld, K, ksplit, NBt, MBt, tprev;
  const float* biasf; long bias_ms;
  bf16* out_bf; long out_ms; int out_ld;
  float* out_f; long outf_ms;
  const bf16* baseb; long baseb_ms;
  const float* temb; long temb_ms;
  const float* feff; long feff_ms;
  const float* prevp;       // part buffer (read) [m][b][4][2]
  const float* ob2;         // opb2 [m][2]
  const float* w2;          // opW2 [m][2][512]
  float* part;              // part buffer (write, EP_OUT)
  float* cbuf; long c_ms;
  bf16* hout; long h_ms;
  bf16* hout2; float* cbuf2;
};

enum { EP_RELU = 0, EP_BF16 = 1, EP_F32 = 2, EP_INIT = 3, EP_LSTM = 4, EP_OUT = 5 };

template<int EP, bool SPLIT, bool FB>
__global__ __launch_bounds__(256, 2)
void gemm_k(GArgs a)
{
  __shared__ __attribute__((aligned(16))) char smem[33792];
  char* As = smem;
  char* Bs = smem + 16384;
  float* Gf = (float*)smem;

  // XCD-aware bijective swizzle (gridDim.x divisible by 8)
  const int id  = blockIdx.x;
  const int id2 = (id & 7) * ((int)gridDim.x >> 3) + (id >> 3);
  const int per = a.MBt * a.NBt;
  const int m   = id2 / per;
  const int rem = id2 - m * per;
  const int mb  = rem / a.NBt;
  const int nb  = rem - mb * a.NBt;

  const int tid = threadIdx.x;
  const int lane = tid & 63;
  const int wid  = tid >> 6;
  const int wr = wid >> 1, wc = wid & 1;

  const bf16* A1m = a.A1 + (long)m * a.a1_ms;
  const bf16* A2m = SPLIT ? (a.A2 + (long)m * a.a2_ms) : nullptr;
  const bf16* Bm  = a.Bw + (long)m * a.b_ms + (long)nb * 128 * a.K;

  f32x4 acc[4][4];
  #pragma unroll
  for (int i = 0; i < 4; ++i)
    #pragma unroll
    for (int j = 0; j < 4; ++j) acc[i][j] = f32x4{0.f, 0.f, 0.f, 0.f};

  // ---- async staging setup ----
  const int rl = lane >> 3;
  const int sg = (lane & 7) ^ rl;
  const bf16* a1B[4]; const bf16* a2B[4]; const bf16* bB[4];
  char* ldA[4]; char* ldB[4];
  #pragma unroll
  for (int c = 0; c < 4; ++c){
    int rt = (wid * 4 + c) * 8 + rl;
    a1B[c] = A1m + (long)(mb * 128 + rt) * a.a_ld + sg * 8;
    if (SPLIT) a2B[c] = A2m + (long)(mb * 128 + rt) * a.a_ld + sg * 8;
    bB[c]  = Bm + (long)rt * a.K + sg * 8;
    ldA[c] = As + (wid * 4 + c) * 1024;
    ldB[c] = Bs + (wid * 4 + c) * 1024;
  }
  auto STAGE = [&](int kb){
    int kcol = kb << 6;
    if (SPLIT && kcol >= a.ksplit){
      int kl = kcol - a.ksplit;
      #pragma unroll
      for (int c = 0; c < 4; ++c){ gload16(a2B[c] + kl, ldA[c]); gload16(bB[c] + kcol, ldB[c]); }
    } else {
      #pragma unroll
      for (int c = 0; c < 4; ++c){ gload16(a1B[c] + kcol, ldA[c]); gload16(bB[c] + kcol, ldB[c]); }
    }
  };

  const int nk = a.K >> 6;
  STAGE(0);
  for (int kb = 0; kb < nk; ++kb){
    __syncthreads();                 // drains vmcnt: stage(kb) visible
    bf16x8 af[2][4], bg[2][4];
    #pragma unroll
    for (int ks = 0; ks < 2; ++ks){
      #pragma unroll
      for (int f = 0; f < 4; ++f){
        int rr = wr * 64 + f * 16 + (lane & 15);
        int kB = ks * 64 + ((lane >> 4) << 4);
        af[ks][f] = *(const bf16x8*)(As + rr * 128 + (kB ^ ((rr & 7) << 4)));
        int rb = wc * 64 + f * 16 + (lane & 15);
        bg[ks][f] = *(const bf16x8*)(Bs + rb * 128 + (kB ^ ((rb & 7) << 4)));
      }
    }
    __syncthreads();                 // frag reads landed; LDS free
    if (kb + 1 < nk) STAGE(kb + 1);  // async prefetch while MFMAs run
    #pragma unroll
    for (int ks = 0; ks < 2; ++ks)
      #pragma unroll
      for (int i = 0; i < 4; ++i)
        #pragma unroll
        for (int j = 0; j < 4; ++j)
          acc[i][j] = __builtin_amdgcn_mfma_f32_16x16x32_bf16(af[ks][i], bg[ks][j], acc[i][j], 0, 0, 0);
  }

  // ---- EP_LSTM: register-direct. acc[i][g][q] holds gate g for
  //      h-col jh = nb*32 + wc*16 + jl, row b = mb*128+wr*64+i*16+(lane>>4)*4+q.
  if constexpr (EP == EP_LSTM){
    const int jl = lane & 15;
    const int qr = lane >> 4;
    const int jh = nb * 32 + wc * 16 + jl;
    const long pbase = (long)nb * 128 + wc * 64 + jl;
    float addv[4], f0v[4], f1v[4];
    #pragma unroll
    for (int g = 0; g < 4; ++g){
      long p = pbase + g * 16;
      if constexpr (FB){
        addv[g] = a.temb[(long)m * a.temb_ms + p];
        f0v[g]  = a.feff[(long)m * a.feff_ms + p];
        f1v[g]  = a.feff[(long)m * a.feff_ms + 2048 + p];
      } else {
        addv[g] = a.biasf[(long)m * a.bias_ms + p];
      }
    }
    const bf16* bb = FB ? (a.baseb + (long)m * a.baseb_ms + pbase) : nullptr;
    float* cb = a.cbuf + (long)m * a.c_ms + jh;
    bf16*  hb = a.hout + (long)m * a.h_ms + jh;
    #pragma unroll
    for (int i = 0; i < 4; ++i){
      #pragma unroll
      for (int q = 0; q < 4; ++q){
        int b = mb * 128 + wr * 64 + i * 16 + qr * 4 + q;
        float pv0 = 0.f, pv1 = 0.f;
        if constexpr (FB){
          if (a.tprev >= 0){
            const float* pp = a.prevp + ((long)m * 2048 + b) * 8;
            pv0 = pp[0] + pp[2] + pp[4] + pp[6] + a.ob2[m * 2];
            pv1 = pp[1] + pp[3] + pp[5] + pp[7] + a.ob2[m * 2 + 1];
          }
          if (nb == 0 && wc == 0 && jl == 0 && a.tprev >= 1){
            a.out_f[(long)b * 960 + m * 160 + a.tprev * 2 + 0] = pv0;
            a.out_f[(long)b * 960 + m * 160 + a.tprev * 2 + 1] = pv1;
          }
        }
        float g4[4];
        #pragma unroll
        for (int g = 0; g < 4; ++g){
          float v = acc[i][g][q] + addv[g];
          if constexpr (FB){
            v += (float)bb[(long)b * 2048 + g * 16];
            v += pv0 * f0v[g] + pv1 * f1v[g];
          }
          g4[g] = v;
        }
        long ro = (long)b * HD;
        float ci = sigmoidf_(g4[0]), cf = sigmoidf_(g4[1]);
        float cg = tanhf_(g4[2]),    co = sigmoidf_(g4[3]);
        float cn = cf * cb[ro] + ci * cg;
        cb[ro] = cn;
        hb[ro] = (bf16)(co * tanhf_(cn));
      }
    }
    return;
  }

  // ---- EP_OUT: fused out-projection, straight from registers ----
  if constexpr (EP == EP_OUT){
    __syncthreads();
    float* ps = (float*)smem;   // [128][4]: (row, wc*2+o)
    int colbase = wc * 64 + (lane & 15);
    float bv[4], w0v[4], w1v[4];
    #pragma unroll
    for (int j = 0; j < 4; ++j){
      int p = nb * 128 + colbase + j * 16;
      bv[j]  = a.biasf[(long)m * a.bias_ms + p];
      w0v[j] = a.w2[(long)m * 1024 + p];
      w1v[j] = a.w2[(long)m * 1024 + 512 + p];
    }
    #pragma unroll
    for (int i = 0; i < 4; ++i)
      #pragma unroll
      for (int q = 0; q < 4; ++q){
        float s0 = 0.f, s1 = 0.f;
        #pragma unroll
        for (int j = 0; j < 4; ++j){
          float v = fmaxf(acc[i][j][q] + bv[j], 0.0f);
          s0 += v * w0v[j]; s1 += v * w1v[j];
        }
        #pragma unroll
        for (int o2 = 1; o2 < 16; o2 <<= 1){ s0 += __shfl_xor(s0, o2); s1 += __shfl_xor(s1, o2); }
        if ((lane & 15) == 0){
          int row = wr * 64 + i * 16 + ((lane >> 4) << 2) + q;
          ps[row * 4 + wc * 2 + 0] = s0;
          ps[row * 4 + wc * 2 + 1] = s1;
        }
      }
    __syncthreads();
    if (tid < 128){
      int b = mb * 128 + tid;
      float o0 = ps[tid * 4 + 0] + ps[tid * 4 + 2];
      float o1 = ps[tid * 4 + 1] + ps[tid * 4 + 3];
      a.part[((long)m * 2048 + b) * 8 + nb * 2 + 0] = o0;
      a.part[((long)m * 2048 + b) * 8 + nb * 2 + 1] = o1;
    }
    return;
  }

  // ---- generic epilogues via LDS G tile, two 64-col passes (precompute only)
  #pragma unroll 1
  for (int ph = 0; ph < 2; ++ph){
    __syncthreads();
    if (wc == ph){
      #pragma unroll
      for (int i = 0; i < 4; ++i)
        #pragma unroll
        for (int j = 0; j < 4; ++j)
          #pragma unroll
          for (int q = 0; q < 4; ++q){
            int rr = wr * 64 + i * 16 + ((lane >> 4) << 2) + q;
            int cc = j * 16 + (lane & 15);
            Gf[rr * 66 + cc] = acc[i][j][q];
          }
    }
    __syncthreads();

    #pragma unroll 1
    for (int it = 0; it < 4; ++it){
      int u = it * 256 + tid;
      int r = u >> 3, cg = u & 7;
      int b = mb * 128 + r;
      int p0 = nb * 128 + ph * 64 + cg * 8;
      float v[8];
      #pragma unroll
      for (int k2 = 0; k2 < 8; ++k2){
        v[k2] = Gf[r * 66 + cg * 8 + k2];
        if (a.biasf) v[k2] += a.biasf[(long)m * a.bias_ms + p0 + k2];
        if constexpr (EP == EP_RELU) v[k2] = fmaxf(v[k2], 0.0f);
      }
      if constexpr (EP == EP_F32){
        float* dst = a.out_f + (long)m * a.outf_ms + (long)b * a.out_ld + p0;
        #pragma unroll
        for (int k2 = 0; k2 < 8; ++k2) dst[k2] = v[k2];
      } else if constexpr (EP == EP_INIT){
        if (p0 < HD){
          bf16x8 ov;
          #pragma unroll
          for (int k2 = 0; k2 < 8; ++k2) ov[k2] = (bf16)v[k2];
          *(bf16x8*)(a.hout  + (long)m * a.h_ms + (long)b * HD + p0) = ov;
          *(bf16x8*)(a.hout2 + (long)m * a.h_ms + (long)b * HD + p0) = ov;
        } else {
          int p1 = p0 - HD;
          float* d1 = a.cbuf  + (long)m * a.c_ms + (long)b * HD + p1;
          float* d2 = a.cbuf2 + (long)m * a.c_ms + (long)b * HD + p1;
          #pragma unroll
          for (int k2 = 0; k2 < 8; ++k2){ d1[k2] = v[k2]; d2[k2] = v[k2]; }
        }
      } else {
        bf16x8 ov;
        #pragma unroll
        for (int k2 = 0; k2 < 8; ++k2) ov[k2] = (bf16)v[k2];
        *(bf16x8*)(a.out_bf + (long)m * a.out_ms + (long)b * a.out_ld + p0) = ov;
      }
    }
  }
}

// ---------------------------------------------------------------------------
extern "C" void kernel_launch(void* const* d_in, const int* in_sizes, int n_in,
                              void* d_out, int out_size, void* d_ws, size_t ws_size,
                              hipStream_t stream)
{
  (void)in_sizes; (void)n_in; (void)out_size;
  const float* X     = (const float*)d_in[0];
  const float* mdW1  = (const float*)d_in[1];
  const float* mdb1  = (const float*)d_in[2];
  const float* mdW2  = (const float*)d_in[3];
  const float* mdb2  = (const float*)d_in[4];
  const float* mdW3  = (const float*)d_in[5];
  const float* mdb3  = (const float*)d_in[6];
  const float* ihW   = (const float*)d_in[7];
  const float* ihb   = (const float*)d_in[8];
  const float* tpW1  = (const float*)d_in[9];
  const float* tpb1  = (const float*)d_in[10];
  const float* tpW2  = (const float*)d_in[11];
  const float* tpb2  = (const float*)d_in[12];
  const float* fbW   = (const float*)d_in[13];
  const float* fbb   = (const float*)d_in[14];
  const float* l0Wih = (const float*)d_in[15];
  const float* l0bih = (const float*)d_in[16];
  const float* l0Whh = (const float*)d_in[17];
  const float* l0bhh = (const float*)d_in[18];
  const float* l1Wih = (const float*)d_in[19];
  const float* l1bih = (const float*)d_in[20];
  const float* l1Whh = (const float*)d_in[21];
  const float* l1bhh = (const float*)d_in[22];
  const float* opW1  = (const float*)d_in[23];
  const float* opb1  = (const float*)d_in[24];
  const float* opW2  = (const float*)d_in[25];
  const float* opb2  = (const float*)d_in[26];
  const float* cfW1  = (const float*)d_in[27];
  const float* cfb1  = (const float*)d_in[28];
  const float* cfW2  = (const float*)d_in[29];
  const float* cfb2  = (const float*)d_in[30];
  float* out = (float*)d_out;

  // ---- static arena (liveness-aliased). Total = 211,009,536 B ----
  const size_t NEED = 211009536;
  if (ws_size < NEED){
    k_diag<<<1, 64, 0, stream>>>(out, (float)(ws_size >> 20));
    return;
  }
  char* ws = (char*)d_ws;
  const long BH = (long)BATCH * HD;

  // persistent (loop-live)
  bf16*  Wp0     = (bf16*) (ws + 0);           // 12,582,912
  bf16*  Wp1     = (bf16*) (ws + 12582912);    // 25,165,824
  bf16*  WpO     = (bf16*) (ws + 37748736);    //  3,145,728
  bf16*  base0p  = (bf16*) (ws + 40894464);    // 50,331,648
  float* tembW0p = (float*)(ws + 91226112);    //  6,291,456
  float* bias1p  = (float*)(ws + 97517568);    //     49,152
  float* Feffp   = (float*)(ws + 97566720);    //     98,304
  char*  REG     =          ws + 97763328;     // 100,663,296 (h0|h1|c0|c1)
  bf16*  h0b     = (bf16*) (REG + 0);
  bf16*  h1b     = (bf16*) (REG + 25165824);
  float* c0      = (float*)(REG + 50331648);
  float* c1      = (float*)(REG + 75497472);
  char*  MREG    =          ws + 198426624;    // 12,582,912

  // precompute temporaries inside REG (dead before EP_INIT writes h/c)
  bf16*  W0ip    = (bf16*) (REG + 0);
  bf16*  mdW1p   = (bf16*) (REG + 12582912);
  bf16*  mdW2p   = (bf16*) (REG + 18874368);
  bf16*  mdW3p   = (bf16*) (REG + 25165824);
  bf16*  tembb   = (bf16*) (REG + 28311552);
  float* bias0p  = (float*)(REG + 28442624);
  bf16*  lt1     = (bf16*) (REG + 28491776);
  bf16*  t1buf   = (bf16*) (REG + 29540352);
  bf16*  t2buf   = (bf16*) (REG + 54706176);
  bf16*  mfbuf   = (bf16*) (REG + 67289088);
  // MREG: precompute temporaries + loop-live part buffer (disjoint)
  bf16*  xb      = (bf16*) (MREG + 0);         //  2,097,152
  bf16*  ihWp    = (bf16*) (MREG + 2097152);   //  6,291,456
  bf16*  cfW1p   = (bf16*) (MREG + 8388608);   //    262,144
  float* part    = (float*)(MREG + 8650752);   //    393,216  [m][b][4][2]

  // ---- pack / convert ----
  k_pack<false,false><<<dim3(512),  256, 0, stream>>>(xb,    X,     nullptr, 512,  2048, 512);
  k_pack<true ,false><<<dim3(3072), 256, 0, stream>>>(Wp0,   l0Whh, nullptr, 512,  2048, 512);
  k_pack<true ,false><<<dim3(3072), 256, 0, stream>>>(W0ip,  l0Wih, nullptr, 512,  2048, 512);
  k_pack<true ,true ><<<dim3(6144), 256, 0, stream>>>(Wp1,   l1Wih, l1Whh,   1024, 2048, 512);
  k_pack<false,false><<<dim3(768),  256, 0, stream>>>(WpO,   opW1,  nullptr, 512,  512,  512);
  k_pack<false,false><<<dim3(1536), 256, 0, stream>>>(mdW1p, mdW1,  nullptr, 512,  1024, 512);
  k_pack<false,false><<<dim3(1536), 256, 0, stream>>>(mdW2p, mdW2,  nullptr, 1024, 512,  1024);
  k_pack<false,false><<<dim3(768),  256, 0, stream>>>(mdW3p, mdW3,  nullptr, 512,  512,  512);
  k_pack<false,false><<<dim3(1536), 256, 0, stream>>>(ihWp,  ihW,   nullptr, 512,  1024, 512);
  k_pack<false,false><<<dim3(64),   256, 0, stream>>>(cfW1p, cfW1,  nullptr, 512,  256,  512);

  k_temb  <<<dim3(128), 256, 0, stream>>>(tembb, tpW1, tpb1, tpW2, tpb2);
  k_biases<<<dim3(48),  256, 0, stream>>>(bias0p, bias1p, l0bih, l0bhh, l1bih, l1bhh, l0Wih, fbb);
  k_feffp <<<dim3(96),  256, 0, stream>>>(Feffp, fbW, l0Wih);
  k_zero  <<<dim3(384), 256, 0, stream>>>(part, out);

  // ---- precompute GEMMs (order matters for arena aliasing) ----
  { GArgs g{}; g.A1 = xb; g.a1_ms = 0; g.a_ld = 512; g.Bw = mdW1p; g.b_ms = (long)1024*512;
    g.K = 512; g.ksplit = 512; g.NBt = 8; g.MBt = 16; g.biasf = mdb1; g.bias_ms = 1024;
    g.out_bf = t1buf; g.out_ms = (long)2048*1024; g.out_ld = 1024;
    gemm_k<EP_RELU,false,false><<<dim3(16*8*6), 256, 0, stream>>>(g); }
  { GArgs g{}; g.A1 = t1buf; g.a1_ms = (long)2048*1024; g.a_ld = 1024; g.Bw = mdW2p; g.b_ms = (long)512*1024;
    g.K = 1024; g.ksplit = 1024; g.NBt = 4; g.MBt = 16; g.biasf = mdb2; g.bias_ms = 512;
    g.out_bf = t2buf; g.out_ms = BH; g.out_ld = 512;
    gemm_k<EP_RELU,false,false><<<dim3(16*4*6), 256, 0, stream>>>(g); }
  { GArgs g{}; g.A1 = t2buf; g.a1_ms = BH; g.a_ld = 512; g.Bw = mdW3p; g.b_ms = (long)512*512;
    g.K = 512; g.ksplit = 512; g.NBt = 4; g.MBt = 16; g.biasf = mdb3; g.bias_ms = 512;
    g.out_bf = mfbuf; g.out_ms = BH; g.out_ld = 512;
    gemm_k<EP_BF16,false,false><<<dim3(16*4*6), 256, 0, stream>>>(g); }
  { GArgs g{}; g.A1 = tembb; g.a1_ms = 0; g.a_ld = 512; g.Bw = W0ip; g.b_ms = (long)2048*512;
    g.K = 512; g.ksplit = 512; g.NBt = 16; g.MBt = 1; g.biasf = nullptr;
    g.out_f = tembW0p; g.outf_ms = (long)128*2048; g.out_ld = 2048;
    gemm_k<EP_F32,false,false><<<dim3(1*16*6), 256, 0, stream>>>(g); }
  // base0 = mf @ W0i.T + bias0p
  { GArgs g{}; g.A1 = mfbuf; g.a1_ms = BH; g.a_ld = 512; g.Bw = W0ip; g.b_ms = (long)2048*512;
    g.K = 512; g.ksplit = 512; g.NBt = 16; g.MBt = 16; g.biasf = bias0p; g.bias_ms = 2048;
    g.out_bf = base0p; g.out_ms = (long)2048*2048; g.out_ld = 2048;
    gemm_k<EP_BF16,false,false><<<dim3(16*16*6), 256, 0, stream>>>(g); }
  { GArgs g{}; g.A1 = xb; g.a1_ms = 0; g.a_ld = 512; g.Bw = cfW1p; g.b_ms = 0;
    g.K = 512; g.ksplit = 512; g.NBt = 2; g.MBt = 16; g.biasf = cfb1; g.bias_ms = 0;
    g.out_bf = lt1; g.out_ms = 0; g.out_ld = 256;
    gemm_k<EP_RELU,false,false><<<dim3(16*2*1), 256, 0, stream>>>(g); }
  k_logits<<<dim3(8), 256, 0, stream>>>(lt1, cfW2, cfb2, out + 1966080, out + 1966080 + 12288);
  { GArgs g{}; g.A1 = xb; g.a1_ms = 0; g.a_ld = 512; g.Bw = ihWp; g.b_ms = (long)1024*512;
    g.K = 512; g.ksplit = 512; g.NBt = 8; g.MBt = 16; g.biasf = ihb; g.bias_ms = 1024;
    g.hout = h0b; g.h_ms = BH; g.hout2 = h1b; g.cbuf = c0; g.c_ms = BH; g.cbuf2 = c1;
    gemm_k<EP_INIT,false,false><<<dim3(16*8*6), 256, 0, stream>>>(g); }

  // ---- recurrent loop (3 dispatches/step) ----
  for (int t = 0; t < 80; ++t){
    int cur = t & 1, nxt = cur ^ 1;
    { GArgs g{}; g.A1 = h0b + (size_t)cur * 6 * BH; g.a1_ms = BH; g.a_ld = 512;
      g.Bw = Wp0; g.b_ms = (long)2048*512; g.K = 512; g.ksplit = 512; g.NBt = 16; g.MBt = 16;
      g.tprev = t - 1;
      g.baseb = base0p; g.baseb_ms = (long)2048*2048;
      g.temb = tembW0p + (long)t * 2048; g.temb_ms = (long)128*2048;
      g.feff = Feffp; g.feff_ms = 4096;
      g.prevp = part; g.ob2 = opb2; g.out_f = out;
      g.cbuf = c0; g.c_ms = BH;
      g.hout = h0b + (size_t)nxt * 6 * BH; g.h_ms = BH;
      gemm_k<EP_LSTM,false,true><<<dim3(16*16*6), 256, 0, stream>>>(g); }
    { GArgs g{}; g.A1 = h0b + (size_t)nxt * 6 * BH; g.A2 = h1b + (size_t)cur * 6 * BH;
      g.a1_ms = BH; g.a2_ms = BH; g.a_ld = 512;
      g.Bw = Wp1; g.b_ms = (long)2048*1024; g.K = 1024; g.ksplit = 512; g.NBt = 16; g.MBt = 16;
      g.biasf = bias1p; g.bias_ms = 2048;
      g.cbuf = c1; g.c_ms = BH;
      g.hout = h1b + (size_t)nxt * 6 * BH; g.h_ms = BH;
      gemm_k<EP_LSTM,true,false><<<dim3(16*16*6), 256, 0, stream>>>(g); }
    { GArgs g{}; g.A1 = h1b + (size_t)nxt * 6 * BH; g.a1_ms = BH; g.a_ld = 512;
      g.Bw = WpO; g.b_ms = (long)512*512; g.K = 512; g.ksplit = 512; g.NBt = 4; g.MBt = 16;
      g.biasf = opb1; g.bias_ms = 512;
      g.w2 = opW2; g.part = part;
      gemm_k<EP_OUT,false,false><<<dim3(16*4*6), 256, 0, stream>>>(g); }
  }
  k_red<<<dim3(48), 256, 0, stream>>>(part, opb2, out);
}

// Round 12
// 10313.214 us; speedup vs baseline: 1.2391x; 1.0948x over previous
//
#include <hip/hip_runtime.h>
#include <cstdint>

typedef __bf16 bf16;
typedef __bf16 bf16x8 __attribute__((ext_vector_type(8)));
typedef float f32x4 __attribute__((ext_vector_type(4)));

#define DI __device__ __forceinline__

#define BATCH 2048
#define HD 512
#define NM 6

// fast rcp (v_rcp_f32, ~1ulp) -- avoids full-precision div sequence
DI float rcp_(float x){ return __builtin_amdgcn_rcpf(x); }
DI float sigmoidf_(float x){ return rcp_(1.0f + __expf(-x)); }
DI float tanhf_(float x){
  float a = __expf(-2.0f * fabsf(x));
  float t = (1.0f - a) * rcp_(1.0f + a);
  return __builtin_copysignf(t, x);
}

// async global->LDS, 16B per lane; LDS dest = wave-uniform base + lane*16
DI void gload16(const bf16* g, char* l){
  __builtin_amdgcn_global_load_lds(
    (const __attribute__((address_space(1))) void*)g,
    (__attribute__((address_space(3))) void*)l, 16, 0, 0);
}

// diagnostic: encode ws_size into d_out[0] if workspace is too small
__global__ void k_diag(float* out, float wsmb){
  if (threadIdx.x == 0 && blockIdx.x == 0) out[0] = wsmb * 1.0e6f;
}

// ---------------------------------------------------------------------------
// Weight pack (fp32->bf16, optional gate-pack / dual-source K-concat)
// packed col p: nb=p>>7, hi=(p>>6)&1, g=(p>>4)&3, jl=p&15 -> row g*512+nb*32+hi*16+jl
// ---------------------------------------------------------------------------
template<bool GATES, bool DUAL>
__global__ void k_pack(bf16* __restrict__ dst, const float* __restrict__ s1,
                       const float* __restrict__ s2, int K, int NROW, int ksplit)
{
  long idx = (long)blockIdx.x * 256 + threadIdx.x;
  int kper = K >> 3;
  int k0 = (int)(idx % kper) * 8;
  long rest = idx / kper;
  int p = (int)(rest % NROW);
  int mm = (int)(rest / NROW);
  int r;
  if (GATES){
    int nb2 = p >> 7, hi = (p >> 6) & 1, g = (p >> 4) & 3, jl = p & 15;
    r = g * 512 + nb2 * 32 + hi * 16 + jl;
  } else r = p;
  const float* src;
  if (DUAL){
    if (k0 >= ksplit) src = s2 + ((long)mm * NROW + r) * ksplit + (k0 - ksplit);
    else              src = s1 + ((long)mm * NROW + r) * ksplit + k0;
  } else {
    src = s1 + ((long)mm * NROW + r) * K + k0;
  }
  f32x4 v0 = *(const f32x4*)(src);
  f32x4 v1 = *(const f32x4*)(src + 4);
  bf16x8 o;
  #pragma unroll
  for (int k = 0; k < 4; ++k){ o[k] = (bf16)v0[k]; o[4+k] = (bf16)v1[k]; }
  *(bf16x8*)(dst + ((long)mm * NROW + p) * K + k0) = o;
}

// time embeddings, pre-scaled by 0.5, rows 80..127 zero-padded
__global__ void k_temb(bf16* tembb, const float* tpW1, const float* tpb1,
                       const float* tpW2, const float* tpb2)
{
  int t = blockIdx.x; int tid = threadIdx.x;
  __shared__ float rq[256];
  float tn = (t < 80) ? (float)t / 79.0f : 0.0f;
  rq[tid] = fmaxf(tn * tpW1[tid] + tpb1[tid], 0.0f);
  __syncthreads();
  for (int d = tid; d < 512; d += 256){
    float s = tpb2[d];
    const float* w = tpW2 + d * 256;
    for (int q = 0; q < 256; ++q) s += rq[q] * w[q];
    tembb[t * 512 + d] = (bf16)((t < 80) ? 0.5f * s : 0.0f);
  }
}

// bias0p = b0i + b0h + 0.3 * fb_b @ W0i[:, :256].T (packed); bias1p = b1i + b1h (packed)
__global__ void k_biases(float* bias0p, float* bias1p,
                         const float* l0bih, const float* l0bhh,
                         const float* l1bih, const float* l1bhh,
                         const float* l0Wih, const float* fbb)
{
  int idx = blockIdx.x * 256 + threadIdx.x; // 6*2048
  int m = idx >> 11, p = idx & 2047;
  int nb2 = p >> 7, hi = (p >> 6) & 1, g = (p >> 4) & 3, jl = p & 15;
  int r = g * 512 + nb2 * 32 + hi * 16 + jl;
  bias1p[idx] = l1bih[m * 2048 + r] + l1bhh[m * 2048 + r];
  const float* wrow = l0Wih + ((long)m * 2048 + r) * 512;
  const float* fb = fbb + m * 256;
  float acc = 0.0f;
  for (int q = 0; q < 256; ++q) acc += fb[q] * wrow[q];
  bias0p[idx] = l0bih[m * 2048 + r] + l0bhh[m * 2048 + r] + 0.3f * acc;
}

// Feffp[m][o][p] = 0.3 * sum_q fb_W[m][q][o] * W0i[orig(p)][q]
__global__ void k_feffp(float* feffp, const float* fbW, const float* l0Wih)
{
  int idx = blockIdx.x * 256 + threadIdx.x; // 6*2*2048
  int p = idx & 2047, o = (idx >> 11) & 1, m = idx >> 12;
  int nb2 = p >> 7, hi = (p >> 6) & 1, g = (p >> 4) & 3, jl = p & 15;
  int r = g * 512 + nb2 * 32 + hi * 16 + jl;
  const float* wrow = l0Wih + ((long)m * 2048 + r) * 512;
  float acc = 0.0f;
  for (int q = 0; q < 256; ++q) acc += fbW[((long)m * 256 + q) * 2 + o] * wrow[q];
  feffp[((long)m * 2 + o) * 2048 + p] = 0.3f * acc;
}

// zero part buffer and trajectory[:, :, 0, :]
__global__ void k_zero(float* part, float* traj)
{
  int i = blockIdx.x * 256 + threadIdx.x; // 98304
  part[i] = 0.0f;
  if (i < 24576){
    int od = i & 1, mm = (i >> 1) % 6, b = i / 12;
    traj[b * 960 + mm * 160 + od] = 0.0f;
  }
}

// logits = lt1 @ cf_W2.T + cf_b2 ; confidences = softmax(logits/1.2)
__global__ void k_logits(const bf16* lt1, const float* cfW2, const float* cfb2,
                         float* conf, float* logitsOut)
{
  int b = blockIdx.x * 256 + threadIdx.x; // 2048
  float acc[6];
  #pragma unroll
  for (int mm = 0; mm < 6; ++mm) acc[mm] = cfb2[mm];
  for (int q = 0; q < 256; ++q){
    float xv = (float)lt1[b * 256 + q];
    #pragma unroll
    for (int mm = 0; mm < 6; ++mm) acc[mm] += xv * cfW2[mm * 256 + q];
  }
  float mx = acc[0];
  #pragma unroll
  for (int mm = 1; mm < 6; ++mm) mx = fmaxf(mx, acc[mm]);
  float e[6], s = 0.0f;
  #pragma unroll
  for (int mm = 0; mm < 6; ++mm){ e[mm] = __expf((acc[mm] - mx) * (1.0f / 1.2f)); s += e[mm]; }
  float inv = 1.0f / s;
  #pragma unroll
  for (int mm = 0; mm < 6; ++mm){
    logitsOut[b * 6 + mm] = acc[mm];
    conf[b * 6 + mm] = e[mm] * inv;
  }
}

// final: traj[79] = sum(part) + opb2
__global__ void k_red(const float* part, const float* opb2, float* traj)
{
  int i = blockIdx.x * 256 + threadIdx.x; // 12288
  int m = i >> 11, b = i & 2047;
  const float* pp = part + (long)i * 8;
  float o0 = pp[0] + pp[2] + pp[4] + pp[6] + opb2[m * 2];
  float o1 = pp[1] + pp[3] + pp[5] + pp[7] + opb2[m * 2 + 1];
  traj[(long)b * 960 + m * 160 + 158] = o0;
  traj[(long)b * 960 + m * 160 + 159] = o1;
}

// ---------------------------------------------------------------------------
// Main GEMM: C = A @ Bw.T, 128x128 tile, BK=64, 4 waves, 16x16x32 bf16 MFMA.
// Staging: async global_load_lds dwordx4, LDS linear per wave-op, XOR swizzle
// applied on the per-lane GLOBAL source segment (sg = (lane&7)^(lane>>3)).
// EP_LSTM/EP_OUT register-direct; LSTM gates use v_rcp-based sigmoid/tanh.
// ---------------------------------------------------------------------------
struct GArgs {
  const bf16* A1; const bf16* A2; const bf16* Bw;
  long a1_ms, a2_ms, b_ms;
  int a_ld, K, ksplit, NBt, MBt, tprev;
  const float* biasf; long bias_ms;
  bf16* out_bf; long out_ms; int out_ld;
  float* out_f; long outf_ms;
  const bf16* baseb; long baseb_ms;
  const float* temb; long temb_ms;
  const float* feff; long feff_ms;
  const float* prevp;       // part buffer (read) [m][b][4][2]
  const float* ob2;         // opb2 [m][2]
  const float* w2;          // opW2 [m][2][512]
  float* part;              // part buffer (write, EP_OUT)
  float* cbuf; long c_ms;
  bf16* hout; long h_ms;
  bf16* hout2; float* cbuf2;
};

enum { EP_RELU = 0, EP_BF16 = 1, EP_F32 = 2, EP_INIT = 3, EP_LSTM = 4, EP_OUT = 5 };

template<int EP, bool SPLIT, bool FB>
__global__ __launch_bounds__(256, 2)
void gemm_k(GArgs a)
{
  __shared__ __attribute__((aligned(16))) char smem[33792];
  char* As = smem;
  char* Bs = smem + 16384;
  float* Gf = (float*)smem;

  // XCD-aware bijective swizzle (gridDim.x divisible by 8)
  const int id  = blockIdx.x;
  const int id2 = (id & 7) * ((int)gridDim.x >> 3) + (id >> 3);
  const int per = a.MBt * a.NBt;
  const int m   = id2 / per;
  const int rem = id2 - m * per;
  const int mb  = rem / a.NBt;
  const int nb  = rem - mb * a.NBt;

  const int tid = threadIdx.x;
  const int lane = tid & 63;
  const int wid  = tid >> 6;
  const int wr = wid >> 1, wc = wid & 1;

  const bf16* A1m = a.A1 + (long)m * a.a1_ms;
  const bf16* A2m = SPLIT ? (a.A2 + (long)m * a.a2_ms) : nullptr;
  const bf16* Bm  = a.Bw + (long)m * a.b_ms + (long)nb * 128 * a.K;

  f32x4 acc[4][4];
  #pragma unroll
  for (int i = 0; i < 4; ++i)
    #pragma unroll
    for (int j = 0; j < 4; ++j) acc[i][j] = f32x4{0.f, 0.f, 0.f, 0.f};

  // ---- async staging setup ----
  const int rl = lane >> 3;
  const int sg = (lane & 7) ^ rl;
  const bf16* a1B[4]; const bf16* a2B[4]; const bf16* bB[4];
  char* ldA[4]; char* ldB[4];
  #pragma unroll
  for (int c = 0; c < 4; ++c){
    int rt = (wid * 4 + c) * 8 + rl;
    a1B[c] = A1m + (long)(mb * 128 + rt) * a.a_ld + sg * 8;
    if (SPLIT) a2B[c] = A2m + (long)(mb * 128 + rt) * a.a_ld + sg * 8;
    bB[c]  = Bm + (long)rt * a.K + sg * 8;
    ldA[c] = As + (wid * 4 + c) * 1024;
    ldB[c] = Bs + (wid * 4 + c) * 1024;
  }
  auto STAGE = [&](int kb){
    int kcol = kb << 6;
    if (SPLIT && kcol >= a.ksplit){
      int kl = kcol - a.ksplit;
      #pragma unroll
      for (int c = 0; c < 4; ++c){ gload16(a2B[c] + kl, ldA[c]); gload16(bB[c] + kcol, ldB[c]); }
    } else {
      #pragma unroll
      for (int c = 0; c < 4; ++c){ gload16(a1B[c] + kcol, ldA[c]); gload16(bB[c] + kcol, ldB[c]); }
    }
  };

  const int nk = a.K >> 6;
  STAGE(0);
  for (int kb = 0; kb < nk; ++kb){
    __syncthreads();                 // drains vmcnt: stage(kb) visible
    bf16x8 af[2][4], bg[2][4];
    #pragma unroll
    for (int ks = 0; ks < 2; ++ks){
      #pragma unroll
      for (int f = 0; f < 4; ++f){
        int rr = wr * 64 + f * 16 + (lane & 15);
        int kB = ks * 64 + ((lane >> 4) << 4);
        af[ks][f] = *(const bf16x8*)(As + rr * 128 + (kB ^ ((rr & 7) << 4)));
        int rb = wc * 64 + f * 16 + (lane & 15);
        bg[ks][f] = *(const bf16x8*)(Bs + rb * 128 + (kB ^ ((rb & 7) << 4)));
      }
    }
    __syncthreads();                 // frag reads landed; LDS free
    if (kb + 1 < nk) STAGE(kb + 1);  // async prefetch while MFMAs run
    #pragma unroll
    for (int ks = 0; ks < 2; ++ks)
      #pragma unroll
      for (int i = 0; i < 4; ++i)
        #pragma unroll
        for (int j = 0; j < 4; ++j)
          acc[i][j] = __builtin_amdgcn_mfma_f32_16x16x32_bf16(af[ks][i], bg[ks][j], acc[i][j], 0, 0, 0);
  }

  // ---- EP_LSTM: register-direct. acc[i][g][q] holds gate g for
  //      h-col jh = nb*32 + wc*16 + jl, row b = mb*128+wr*64+i*16+(lane>>4)*4+q.
  if constexpr (EP == EP_LSTM){
    const int jl = lane & 15;
    const int qr = lane >> 4;
    const int jh = nb * 32 + wc * 16 + jl;
    const long pbase = (long)nb * 128 + wc * 64 + jl;
    float addv[4], f0v[4], f1v[4];
    #pragma unroll
    for (int g = 0; g < 4; ++g){
      long p = pbase + g * 16;
      if constexpr (FB){
        addv[g] = a.temb[(long)m * a.temb_ms + p];
        f0v[g]  = a.feff[(long)m * a.feff_ms + p];
        f1v[g]  = a.feff[(long)m * a.feff_ms + 2048 + p];
      } else {
        addv[g] = a.biasf[(long)m * a.bias_ms + p];
      }
    }
    const bf16* bb = FB ? (a.baseb + (long)m * a.baseb_ms + pbase) : nullptr;
    float* cb = a.cbuf + (long)m * a.c_ms + jh;
    bf16*  hb = a.hout + (long)m * a.h_ms + jh;
    #pragma unroll
    for (int i = 0; i < 4; ++i){
      #pragma unroll
      for (int q = 0; q < 4; ++q){
        int b = mb * 128 + wr * 64 + i * 16 + qr * 4 + q;
        float pv0 = 0.f, pv1 = 0.f;
        if constexpr (FB){
          if (a.tprev >= 0){
            const float* pp = a.prevp + ((long)m * 2048 + b) * 8;
            f32x4 pa = *(const f32x4*)(pp);
            f32x4 pb = *(const f32x4*)(pp + 4);
            pv0 = pa[0] + pa[2] + pb[0] + pb[2] + a.ob2[m * 2];
            pv1 = pa[1] + pa[3] + pb[1] + pb[3] + a.ob2[m * 2 + 1];
          }
          if (nb == 0 && wc == 0 && jl == 0 && a.tprev >= 1){
            a.out_f[(long)b * 960 + m * 160 + a.tprev * 2 + 0] = pv0;
            a.out_f[(long)b * 960 + m * 160 + a.tprev * 2 + 1] = pv1;
          }
        }
        float g4[4];
        #pragma unroll
        for (int g = 0; g < 4; ++g){
          float v = acc[i][g][q] + addv[g];
          if constexpr (FB){
            v += (float)bb[(long)b * 2048 + g * 16];
            v += pv0 * f0v[g] + pv1 * f1v[g];
          }
          g4[g] = v;
        }
        long ro = (long)b * HD;
        float ci = sigmoidf_(g4[0]), cf = sigmoidf_(g4[1]);
        float cg = tanhf_(g4[2]),    co = sigmoidf_(g4[3]);
        float cn = cf * cb[ro] + ci * cg;
        cb[ro] = cn;
        hb[ro] = (bf16)(co * tanhf_(cn));
      }
    }
    return;
  }

  // ---- EP_OUT: fused out-projection, straight from registers ----
  if constexpr (EP == EP_OUT){
    __syncthreads();
    float* ps = (float*)smem;   // [128][4]: (row, wc*2+o)
    int colbase = wc * 64 + (lane & 15);
    float bv[4], w0v[4], w1v[4];
    #pragma unroll
    for (int j = 0; j < 4; ++j){
      int p = nb * 128 + colbase + j * 16;
      bv[j]  = a.biasf[(long)m * a.bias_ms + p];
      w0v[j] = a.w2[(long)m * 1024 + p];
      w1v[j] = a.w2[(long)m * 1024 + 512 + p];
    }
    #pragma unroll
    for (int i = 0; i < 4; ++i)
      #pragma unroll
      for (int q = 0; q < 4; ++q){
        float s0 = 0.f, s1 = 0.f;
        #pragma unroll
        for (int j = 0; j < 4; ++j){
          float v = fmaxf(acc[i][j][q] + bv[j], 0.0f);
          s0 += v * w0v[j]; s1 += v * w1v[j];
        }
        #pragma unroll
        for (int o2 = 1; o2 < 16; o2 <<= 1){ s0 += __shfl_xor(s0, o2); s1 += __shfl_xor(s1, o2); }
        if ((lane & 15) == 0){
          int row = wr * 64 + i * 16 + ((lane >> 4) << 2) + q;
          ps[row * 4 + wc * 2 + 0] = s0;
          ps[row * 4 + wc * 2 + 1] = s1;
        }
      }
    __syncthreads();
    if (tid < 128){
      int b = mb * 128 + tid;
      float o0 = ps[tid * 4 + 0] + ps[tid * 4 + 2];
      float o1 = ps[tid * 4 + 1] + ps[tid * 4 + 3];
      a.part[((long)m * 2048 + b) * 8 + nb * 2 + 0] = o0;
      a.part[((long)m * 2048 + b) * 8 + nb * 2 + 1] = o1;
    }
    return;
  }

  // ---- generic epilogues via LDS G tile, two 64-col passes (precompute only)
  #pragma unroll 1
  for (int ph = 0; ph < 2; ++ph){
    __syncthreads();
    if (wc == ph){
      #pragma unroll
      for (int i = 0; i < 4; ++i)
        #pragma unroll
        for (int j = 0; j < 4; ++j)
          #pragma unroll
          for (int q = 0; q < 4; ++q){
            int rr = wr * 64 + i * 16 + ((lane >> 4) << 2) + q;
            int cc = j * 16 + (lane & 15);
            Gf[rr * 66 + cc] = acc[i][j][q];
          }
    }
    __syncthreads();

    #pragma unroll 1
    for (int it = 0; it < 4; ++it){
      int u = it * 256 + tid;
      int r = u >> 3, cg = u & 7;
      int b = mb * 128 + r;
      int p0 = nb * 128 + ph * 64 + cg * 8;
      float v[8];
      #pragma unroll
      for (int k2 = 0; k2 < 8; ++k2){
        v[k2] = Gf[r * 66 + cg * 8 + k2];
        if (a.biasf) v[k2] += a.biasf[(long)m * a.bias_ms + p0 + k2];
        if constexpr (EP == EP_RELU) v[k2] = fmaxf(v[k2], 0.0f);
      }
      if constexpr (EP == EP_F32){
        float* dst = a.out_f + (long)m * a.outf_ms + (long)b * a.out_ld + p0;
        #pragma unroll
        for (int k2 = 0; k2 < 8; ++k2) dst[k2] = v[k2];
      } else if constexpr (EP == EP_INIT){
        if (p0 < HD){
          bf16x8 ov;
          #pragma unroll
          for (int k2 = 0; k2 < 8; ++k2) ov[k2] = (bf16)v[k2];
          *(bf16x8*)(a.hout  + (long)m * a.h_ms + (long)b * HD + p0) = ov;
          *(bf16x8*)(a.hout2 + (long)m * a.h_ms + (long)b * HD + p0) = ov;
        } else {
          int p1 = p0 - HD;
          float* d1 = a.cbuf  + (long)m * a.c_ms + (long)b * HD + p1;
          float* d2 = a.cbuf2 + (long)m * a.c_ms + (long)b * HD + p1;
          #pragma unroll
          for (int k2 = 0; k2 < 8; ++k2){ d1[k2] = v[k2]; d2[k2] = v[k2]; }
        }
      } else {
        bf16x8 ov;
        #pragma unroll
        for (int k2 = 0; k2 < 8; ++k2) ov[k2] = (bf16)v[k2];
        *(bf16x8*)(a.out_bf + (long)m * a.out_ms + (long)b * a.out_ld + p0) = ov;
      }
    }
  }
}

// ---------------------------------------------------------------------------
extern "C" void kernel_launch(void* const* d_in, const int* in_sizes, int n_in,
                              void* d_out, int out_size, void* d_ws, size_t ws_size,
                              hipStream_t stream)
{
  (void)in_sizes; (void)n_in; (void)out_size;
  const float* X     = (const float*)d_in[0];
  const float* mdW1  = (const float*)d_in[1];
  const float* mdb1  = (const float*)d_in[2];
  const float* mdW2  = (const float*)d_in[3];
  const float* mdb2  = (const float*)d_in[4];
  const float* mdW3  = (const float*)d_in[5];
  const float* mdb3  = (const float*)d_in[6];
  const float* ihW   = (const float*)d_in[7];
  const float* ihb   = (const float*)d_in[8];
  const float* tpW1  = (const float*)d_in[9];
  const float* tpb1  = (const float*)d_in[10];
  const float* tpW2  = (const float*)d_in[11];
  const float* tpb2  = (const float*)d_in[12];
  const float* fbW   = (const float*)d_in[13];
  const float* fbb   = (const float*)d_in[14];
  const float* l0Wih = (const float*)d_in[15];
  const float* l0bih = (const float*)d_in[16];
  const float* l0Whh = (const float*)d_in[17];
  const float* l0bhh = (const float*)d_in[18];
  const float* l1Wih = (const float*)d_in[19];
  const float* l1bih = (const float*)d_in[20];
  const float* l1Whh = (const float*)d_in[21];
  const float* l1bhh = (const float*)d_in[22];
  const float* opW1  = (const float*)d_in[23];
  const float* opb1  = (const float*)d_in[24];
  const float* opW2  = (const float*)d_in[25];
  const float* opb2  = (const float*)d_in[26];
  const float* cfW1  = (const float*)d_in[27];
  const float* cfb1  = (const float*)d_in[28];
  const float* cfW2  = (const float*)d_in[29];
  const float* cfb2  = (const float*)d_in[30];
  float* out = (float*)d_out;

  // ---- static arena (liveness-aliased). Total = 211,009,536 B ----
  const size_t NEED = 211009536;
  if (ws_size < NEED){
    k_diag<<<1, 64, 0, stream>>>(out, (float)(ws_size >> 20));
    return;
  }
  char* ws = (char*)d_ws;
  const long BH = (long)BATCH * HD;

  // persistent (loop-live)
  bf16*  Wp0     = (bf16*) (ws + 0);           // 12,582,912
  bf16*  Wp1     = (bf16*) (ws + 12582912);    // 25,165,824
  bf16*  WpO     = (bf16*) (ws + 37748736);    //  3,145,728
  bf16*  base0p  = (bf16*) (ws + 40894464);    // 50,331,648
  float* tembW0p = (float*)(ws + 91226112);    //  6,291,456
  float* bias1p  = (float*)(ws + 97517568);    //     49,152
  float* Feffp   = (float*)(ws + 97566720);    //     98,304
  char*  REG     =          ws + 97763328;     // 100,663,296 (h0|h1|c0|c1)
  bf16*  h0b     = (bf16*) (REG + 0);
  bf16*  h1b     = (bf16*) (REG + 25165824);
  float* c0      = (float*)(REG + 50331648);
  float* c1      = (float*)(REG + 75497472);
  char*  MREG    =          ws + 198426624;    // 12,582,912

  // precompute temporaries inside REG (dead before EP_INIT writes h/c)
  bf16*  W0ip    = (bf16*) (REG + 0);
  bf16*  mdW1p   = (bf16*) (REG + 12582912);
  bf16*  mdW2p   = (bf16*) (REG + 18874368);
  bf16*  mdW3p   = (bf16*) (REG + 25165824);
  bf16*  tembb   = (bf16*) (REG + 28311552);
  float* bias0p  = (float*)(REG + 28442624);
  bf16*  lt1     = (bf16*) (REG + 28491776);
  bf16*  t1buf   = (bf16*) (REG + 29540352);
  bf16*  t2buf   = (bf16*) (REG + 54706176);
  bf16*  mfbuf   = (bf16*) (REG + 67289088);
  // MREG: precompute temporaries + loop-live part buffer (disjoint)
  bf16*  xb      = (bf16*) (MREG + 0);         //  2,097,152
  bf16*  ihWp    = (bf16*) (MREG + 2097152);   //  6,291,456
  bf16*  cfW1p   = (bf16*) (MREG + 8388608);   //    262,144
  float* part    = (float*)(MREG + 8650752);   //    393,216  [m][b][4][2]

  // ---- pack / convert ----
  k_pack<false,false><<<dim3(512),  256, 0, stream>>>(xb,    X,     nullptr, 512,  2048, 512);
  k_pack<true ,false><<<dim3(3072), 256, 0, stream>>>(Wp0,   l0Whh, nullptr, 512,  2048, 512);
  k_pack<true ,false><<<dim3(3072), 256, 0, stream>>>(W0ip,  l0Wih, nullptr, 512,  2048, 512);
  k_pack<true ,true ><<<dim3(6144), 256, 0, stream>>>(Wp1,   l1Wih, l1Whh,   1024, 2048, 512);
  k_pack<false,false><<<dim3(768),  256, 0, stream>>>(WpO,   opW1,  nullptr, 512,  512,  512);
  k_pack<false,false><<<dim3(1536), 256, 0, stream>>>(mdW1p, mdW1,  nullptr, 512,  1024, 512);
  k_pack<false,false><<<dim3(1536), 256, 0, stream>>>(mdW2p, mdW2,  nullptr, 1024, 512,  1024);
  k_pack<false,false><<<dim3(768),  256, 0, stream>>>(mdW3p, mdW3,  nullptr, 512,  512,  512);
  k_pack<false,false><<<dim3(1536), 256, 0, stream>>>(ihWp,  ihW,   nullptr, 512,  1024, 512);
  k_pack<false,false><<<dim3(64),   256, 0, stream>>>(cfW1p, cfW1,  nullptr, 512,  256,  512);

  k_temb  <<<dim3(128), 256, 0, stream>>>(tembb, tpW1, tpb1, tpW2, tpb2);
  k_biases<<<dim3(48),  256, 0, stream>>>(bias0p, bias1p, l0bih, l0bhh, l1bih, l1bhh, l0Wih, fbb);
  k_feffp <<<dim3(96),  256, 0, stream>>>(Feffp, fbW, l0Wih);
  k_zero  <<<dim3(384), 256, 0, stream>>>(part, out);

  // ---- precompute GEMMs (order matters for arena aliasing) ----
  { GArgs g{}; g.A1 = xb; g.a1_ms = 0; g.a_ld = 512; g.Bw = mdW1p; g.b_ms = (long)1024*512;
    g.K = 512; g.ksplit = 512; g.NBt = 8; g.MBt = 16; g.biasf = mdb1; g.bias_ms = 1024;
    g.out_bf = t1buf; g.out_ms = (long)2048*1024; g.out_ld = 1024;
    gemm_k<EP_RELU,false,false><<<dim3(16*8*6), 256, 0, stream>>>(g); }
  { GArgs g{}; g.A1 = t1buf; g.a1_ms = (long)2048*1024; g.a_ld = 1024; g.Bw = mdW2p; g.b_ms = (long)512*1024;
    g.K = 1024; g.ksplit = 1024; g.NBt = 4; g.MBt = 16; g.biasf = mdb2; g.bias_ms = 512;
    g.out_bf = t2buf; g.out_ms = BH; g.out_ld = 512;
    gemm_k<EP_RELU,false,false><<<dim3(16*4*6), 256, 0, stream>>>(g); }
  { GArgs g{}; g.A1 = t2buf; g.a1_ms = BH; g.a_ld = 512; g.Bw = mdW3p; g.b_ms = (long)512*512;
    g.K = 512; g.ksplit = 512; g.NBt = 4; g.MBt = 16; g.biasf = mdb3; g.bias_ms = 512;
    g.out_bf = mfbuf; g.out_ms = BH; g.out_ld = 512;
    gemm_k<EP_BF16,false,false><<<dim3(16*4*6), 256, 0, stream>>>(g); }
  { GArgs g{}; g.A1 = tembb; g.a1_ms = 0; g.a_ld = 512; g.Bw = W0ip; g.b_ms = (long)2048*512;
    g.K = 512; g.ksplit = 512; g.NBt = 16; g.MBt = 1; g.biasf = nullptr;
    g.out_f = tembW0p; g.outf_ms = (long)128*2048; g.out_ld = 2048;
    gemm_k<EP_F32,false,false><<<dim3(1*16*6), 256, 0, stream>>>(g); }
  // base0 = mf @ W0i.T + bias0p
  { GArgs g{}; g.A1 = mfbuf; g.a1_ms = BH; g.a_ld = 512; g.Bw = W0ip; g.b_ms = (long)2048*512;
    g.K = 512; g.ksplit = 512; g.NBt = 16; g.MBt = 16; g.biasf = bias0p; g.bias_ms = 2048;
    g.out_bf = base0p; g.out_ms = (long)2048*2048; g.out_ld = 2048;
    gemm_k<EP_BF16,false,false><<<dim3(16*16*6), 256, 0, stream>>>(g); }
  { GArgs g{}; g.A1 = xb; g.a1_ms = 0; g.a_ld = 512; g.Bw = cfW1p; g.b_ms = 0;
    g.K = 512; g.ksplit = 512; g.NBt = 2; g.MBt = 16; g.biasf = cfb1; g.bias_ms = 0;
    g.out_bf = lt1; g.out_ms = 0; g.out_ld = 256;
    gemm_k<EP_RELU,false,false><<<dim3(16*2*1), 256, 0, stream>>>(g); }
  k_logits<<<dim3(8), 256, 0, stream>>>(lt1, cfW2, cfb2, out + 1966080, out + 1966080 + 12288);
  { GArgs g{}; g.A1 = xb; g.a1_ms = 0; g.a_ld = 512; g.Bw = ihWp; g.b_ms = (long)1024*512;
    g.K = 512; g.ksplit = 512; g.NBt = 8; g.MBt = 16; g.biasf = ihb; g.bias_ms = 1024;
    g.hout = h0b; g.h_ms = BH; g.hout2 = h1b; g.cbuf = c0; g.c_ms = BH; g.cbuf2 = c1;
    gemm_k<EP_INIT,false,false><<<dim3(16*8*6), 256, 0, stream>>>(g); }

  // ---- recurrent loop (3 dispatches/step) ----
  for (int t = 0; t < 80; ++t){
    int cur = t & 1, nxt = cur ^ 1;
    { GArgs g{}; g.A1 = h0b + (size_t)cur * 6 * BH; g.a1_ms = BH; g.a_ld = 512;
      g.Bw = Wp0; g.b_ms = (long)2048*512; g.K = 512; g.ksplit = 512; g.NBt = 16; g.MBt = 16;
      g.tprev = t - 1;
      g.baseb = base0p; g.baseb_ms = (long)2048*2048;
      g.temb = tembW0p + (long)t * 2048; g.temb_ms = (long)128*2048;
      g.feff = Feffp; g.feff_ms = 4096;
      g.prevp = part; g.ob2 = opb2; g.out_f = out;
      g.cbuf = c0; g.c_ms = BH;
      g.hout = h0b + (size_t)nxt * 6 * BH; g.h_ms = BH;
      gemm_k<EP_LSTM,false,true><<<dim3(16*16*6), 256, 0, stream>>>(g); }
    { GArgs g{}; g.A1 = h0b + (size_t)nxt * 6 * BH; g.A2 = h1b + (size_t)cur * 6 * BH;
      g.a1_ms = BH; g.a2_ms = BH; g.a_ld = 512;
      g.Bw = Wp1; g.b_ms = (long)2048*1024; g.K = 1024; g.ksplit = 512; g.NBt = 16; g.MBt = 16;
      g.biasf = bias1p; g.bias_ms = 2048;
      g.cbuf = c1; g.c_ms = BH;
      g.hout = h1b + (size_t)nxt * 6 * BH; g.h_ms = BH;
      gemm_k<EP_LSTM,true,false><<<dim3(16*16*6), 256, 0, stream>>>(g); }
    { GArgs g{}; g.A1 = h1b + (size_t)nxt * 6 * BH; g.a1_ms = BH; g.a_ld = 512;
      g.Bw = WpO; g.b_ms = (long)512*512; g.K = 512; g.ksplit = 512; g.NBt = 4; g.MBt = 16;
      g.biasf = opb1; g.bias_ms = 512;
      g.w2 = opW2; g.part = part;
      gemm_k<EP_OUT,false,false><<<dim3(16*4*6), 256, 0, stream>>>(g); }
  }
  k_red<<<dim3(48), 256, 0, stream>>>(part, opb2, out);
}

// Round 13
// 9376.464 us; speedup vs baseline: 1.3629x; 1.0999x over previous
//
#include <hip/hip_runtime.h>
#include <cstdint>

typedef __bf16 bf16;
typedef __bf16 bf16x8 __attribute__((ext_vector_type(8)));
typedef float f32x4 __attribute__((ext_vector_type(4)));

#define DI __device__ __forceinline__

#define BATCH 2048
#define HD 512
#define NM 6

// fast rcp (v_rcp_f32, ~1ulp) -- avoids full-precision div sequence
DI float rcp_(float x){ return __builtin_amdgcn_rcpf(x); }
DI float sigmoidf_(float x){ return rcp_(1.0f + __expf(-x)); }
DI float tanhf_(float x){
  float a = __expf(-2.0f * fabsf(x));
  float t = (1.0f - a) * rcp_(1.0f + a);
  return __builtin_copysignf(t, x);
}

// async global->LDS, 16B per lane; LDS dest = wave-uniform base + lane*16
DI void gload16(const bf16* g, char* l){
  __builtin_amdgcn_global_load_lds(
    (const __attribute__((address_space(1))) void*)g,
    (__attribute__((address_space(3))) void*)l, 16, 0, 0);
}

// diagnostic: encode ws_size into d_out[0] if workspace is too small
__global__ void k_diag(float* out, float wsmb){
  if (threadIdx.x == 0 && blockIdx.x == 0) out[0] = wsmb * 1.0e6f;
}

// ---------------------------------------------------------------------------
// Weight pack (fp32->bf16, optional gate-pack / dual-source K-concat)
// packed col p: nb=p>>7, hi=(p>>6)&1, g=(p>>4)&3, jl=p&15 -> row g*512+nb*32+hi*16+jl
// ---------------------------------------------------------------------------
template<bool GATES, bool DUAL>
__global__ void k_pack(bf16* __restrict__ dst, const float* __restrict__ s1,
                       const float* __restrict__ s2, int K, int NROW, int ksplit)
{
  long idx = (long)blockIdx.x * 256 + threadIdx.x;
  int kper = K >> 3;
  int k0 = (int)(idx % kper) * 8;
  long rest = idx / kper;
  int p = (int)(rest % NROW);
  int mm = (int)(rest / NROW);
  int r;
  if (GATES){
    int nb2 = p >> 7, hi = (p >> 6) & 1, g = (p >> 4) & 3, jl = p & 15;
    r = g * 512 + nb2 * 32 + hi * 16 + jl;
  } else r = p;
  const float* src;
  if (DUAL){
    if (k0 >= ksplit) src = s2 + ((long)mm * NROW + r) * ksplit + (k0 - ksplit);
    else              src = s1 + ((long)mm * NROW + r) * ksplit + k0;
  } else {
    src = s1 + ((long)mm * NROW + r) * K + k0;
  }
  f32x4 v0 = *(const f32x4*)(src);
  f32x4 v1 = *(const f32x4*)(src + 4);
  bf16x8 o;
  #pragma unroll
  for (int k = 0; k < 4; ++k){ o[k] = (bf16)v0[k]; o[4+k] = (bf16)v1[k]; }
  *(bf16x8*)(dst + ((long)mm * NROW + p) * K + k0) = o;
}

// time embeddings, pre-scaled by 0.5, rows 80..127 zero-padded
__global__ void k_temb(bf16* tembb, const float* tpW1, const float* tpb1,
                       const float* tpW2, const float* tpb2)
{
  int t = blockIdx.x; int tid = threadIdx.x;
  __shared__ float rq[256];
  float tn = (t < 80) ? (float)t / 79.0f : 0.0f;
  rq[tid] = fmaxf(tn * tpW1[tid] + tpb1[tid], 0.0f);
  __syncthreads();
  for (int d = tid; d < 512; d += 256){
    float s = tpb2[d];
    const float* w = tpW2 + d * 256;
    for (int q = 0; q < 256; ++q) s += rq[q] * w[q];
    tembb[t * 512 + d] = (bf16)((t < 80) ? 0.5f * s : 0.0f);
  }
}

// bias0p = b0i + b0h + 0.3 * fb_b @ W0i[:, :256].T (packed); bias1p = b1i + b1h (packed)
__global__ void k_biases(float* bias0p, float* bias1p,
                         const float* l0bih, const float* l0bhh,
                         const float* l1bih, const float* l1bhh,
                         const float* l0Wih, const float* fbb)
{
  int idx = blockIdx.x * 256 + threadIdx.x; // 6*2048
  int m = idx >> 11, p = idx & 2047;
  int nb2 = p >> 7, hi = (p >> 6) & 1, g = (p >> 4) & 3, jl = p & 15;
  int r = g * 512 + nb2 * 32 + hi * 16 + jl;
  bias1p[idx] = l1bih[m * 2048 + r] + l1bhh[m * 2048 + r];
  const float* wrow = l0Wih + ((long)m * 2048 + r) * 512;
  const float* fb = fbb + m * 256;
  float acc = 0.0f;
  for (int q = 0; q < 256; ++q) acc += fb[q] * wrow[q];
  bias0p[idx] = l0bih[m * 2048 + r] + l0bhh[m * 2048 + r] + 0.3f * acc;
}

// Feffp[m][o][p] = 0.3 * sum_q fb_W[m][q][o] * W0i[orig(p)][q]
__global__ void k_feffp(float* feffp, const float* fbW, const float* l0Wih)
{
  int idx = blockIdx.x * 256 + threadIdx.x; // 6*2*2048
  int p = idx & 2047, o = (idx >> 11) & 1, m = idx >> 12;
  int nb2 = p >> 7, hi = (p >> 6) & 1, g = (p >> 4) & 3, jl = p & 15;
  int r = g * 512 + nb2 * 32 + hi * 16 + jl;
  const float* wrow = l0Wih + ((long)m * 2048 + r) * 512;
  float acc = 0.0f;
  for (int q = 0; q < 256; ++q) acc += fbW[((long)m * 256 + q) * 2 + o] * wrow[q];
  feffp[((long)m * 2 + o) * 2048 + p] = 0.3f * acc;
}

// zero part buffer and trajectory[:, :, 0, :]
__global__ void k_zero(float* part, float* traj)
{
  int i = blockIdx.x * 256 + threadIdx.x; // 98304
  part[i] = 0.0f;
  if (i < 24576){
    int od = i & 1, mm = (i >> 1) % 6, b = i / 12;
    traj[b * 960 + mm * 160 + od] = 0.0f;
  }
}

// logits = lt1 @ cf_W2.T + cf_b2 ; confidences = softmax(logits/1.2)
__global__ void k_logits(const bf16* lt1, const float* cfW2, const float* cfb2,
                         float* conf, float* logitsOut)
{
  int b = blockIdx.x * 256 + threadIdx.x; // 2048
  float acc[6];
  #pragma unroll
  for (int mm = 0; mm < 6; ++mm) acc[mm] = cfb2[mm];
  for (int q = 0; q < 256; ++q){
    float xv = (float)lt1[b * 256 + q];
    #pragma unroll
    for (int mm = 0; mm < 6; ++mm) acc[mm] += xv * cfW2[mm * 256 + q];
  }
  float mx = acc[0];
  #pragma unroll
  for (int mm = 1; mm < 6; ++mm) mx = fmaxf(mx, acc[mm]);
  float e[6], s = 0.0f;
  #pragma unroll
  for (int mm = 0; mm < 6; ++mm){ e[mm] = __expf((acc[mm] - mx) * (1.0f / 1.2f)); s += e[mm]; }
  float inv = 1.0f / s;
  #pragma unroll
  for (int mm = 0; mm < 6; ++mm){
    logitsOut[b * 6 + mm] = acc[mm];
    conf[b * 6 + mm] = e[mm] * inv;
  }
}

// final: traj[79] = sum(part) + opb2
__global__ void k_red(const float* part, const float* opb2, float* traj)
{
  int i = blockIdx.x * 256 + threadIdx.x; // 12288
  int m = i >> 11, b = i & 2047;
  const float* pp = part + (long)i * 8;
  float o0 = pp[0] + pp[2] + pp[4] + pp[6] + opb2[m * 2];
  float o1 = pp[1] + pp[3] + pp[5] + pp[7] + opb2[m * 2 + 1];
  traj[(long)b * 960 + m * 160 + 158] = o0;
  traj[(long)b * 960 + m * 160 + 159] = o1;
}

// ---------------------------------------------------------------------------
// Main GEMM: C = A @ Bw.T, 128x128 tile, BK=64, 4 waves, 16x16x32 bf16 MFMA.
// Async global_load_lds staging (XOR swizzle on global source segment).
// EP_LSTM FB: base0p loaded as MFMA C-in (prologue, latency hidden under
// K-loop); prevout sums computed once per row into a 1KB LDS table.
// ---------------------------------------------------------------------------
struct GArgs {
  const bf16* A1; const bf16* A2; const bf16* Bw;
  long a1_ms, a2_ms, b_ms;
  int a_ld, K, ksplit, NBt, MBt, tprev;
  const float* biasf; long bias_ms;
  bf16* out_bf; long out_ms; int out_ld;
  float* out_f; long outf_ms;
  const bf16* baseb; long baseb_ms;
  const float* temb; long temb_ms;
  const float* feff; long feff_ms;
  const float* prevp;       // part buffer (read) [m][b][4][2]
  const float* ob2;         // opb2 [m][2]
  const float* w2;          // opW2 [m][2][512]
  float* part;              // part buffer (write, EP_OUT)
  float* cbuf; long c_ms;
  bf16* hout; long h_ms;
  bf16* hout2; float* cbuf2;
};

enum { EP_RELU = 0, EP_BF16 = 1, EP_F32 = 2, EP_INIT = 3, EP_LSTM = 4, EP_OUT = 5 };

template<int EP, bool SPLIT, bool FB>
__global__ __launch_bounds__(256, 2)
void gemm_k(GArgs a)
{
  __shared__ __attribute__((aligned(16))) char smem[33792];
  char* As = smem;
  char* Bs = smem + 16384;
  float* Gf = (float*)smem;

  // XCD-aware bijective swizzle (gridDim.x divisible by 8)
  const int id  = blockIdx.x;
  const int id2 = (id & 7) * ((int)gridDim.x >> 3) + (id >> 3);
  const int per = a.MBt * a.NBt;
  const int m   = id2 / per;
  const int rem = id2 - m * per;
  const int mb  = rem / a.NBt;
  const int nb  = rem - mb * a.NBt;

  const int tid = threadIdx.x;
  const int lane = tid & 63;
  const int wid  = tid >> 6;
  const int wr = wid >> 1, wc = wid & 1;

  const bf16* A1m = a.A1 + (long)m * a.a1_ms;
  const bf16* A2m = SPLIT ? (a.A2 + (long)m * a.a2_ms) : nullptr;
  const bf16* Bm  = a.Bw + (long)m * a.b_ms + (long)nb * 128 * a.K;

  f32x4 acc[4][4];
  if constexpr (EP == EP_LSTM && FB){
    // base0 as MFMA C-in: loads issue at prologue, latency hides under K-loop
    const int jl_ = lane & 15;
    const int qr_ = lane >> 4;
    const bf16* bb0 = a.baseb + (long)m * a.baseb_ms
                      + (long)nb * 128 + wc * 64 + jl_;
    #pragma unroll
    for (int i = 0; i < 4; ++i)
      #pragma unroll
      for (int q = 0; q < 4; ++q){
        long b = mb * 128 + wr * 64 + i * 16 + qr_ * 4 + q;
        #pragma unroll
        for (int g = 0; g < 4; ++g)
          acc[i][g][q] = (float)bb0[b * 2048 + g * 16];
      }
  } else {
    #pragma unroll
    for (int i = 0; i < 4; ++i)
      #pragma unroll
      for (int j = 0; j < 4; ++j) acc[i][j] = f32x4{0.f, 0.f, 0.f, 0.f};
  }

  // ---- async staging setup ----
  const int rl = lane >> 3;
  const int sg = (lane & 7) ^ rl;
  const bf16* a1B[4]; const bf16* a2B[4]; const bf16* bB[4];
  char* ldA[4]; char* ldB[4];
  #pragma unroll
  for (int c = 0; c < 4; ++c){
    int rt = (wid * 4 + c) * 8 + rl;
    a1B[c] = A1m + (long)(mb * 128 + rt) * a.a_ld + sg * 8;
    if (SPLIT) a2B[c] = A2m + (long)(mb * 128 + rt) * a.a_ld + sg * 8;
    bB[c]  = Bm + (long)rt * a.K + sg * 8;
    ldA[c] = As + (wid * 4 + c) * 1024;
    ldB[c] = Bs + (wid * 4 + c) * 1024;
  }
  auto STAGE = [&](int kb){
    int kcol = kb << 6;
    if (SPLIT && kcol >= a.ksplit){
      int kl = kcol - a.ksplit;
      #pragma unroll
      for (int c = 0; c < 4; ++c){ gload16(a2B[c] + kl, ldA[c]); gload16(bB[c] + kcol, ldB[c]); }
    } else {
      #pragma unroll
      for (int c = 0; c < 4; ++c){ gload16(a1B[c] + kcol, ldA[c]); gload16(bB[c] + kcol, ldB[c]); }
    }
  };

  const int nk = a.K >> 6;
  STAGE(0);
  for (int kb = 0; kb < nk; ++kb){
    __syncthreads();                 // drains vmcnt: stage(kb) visible
    bf16x8 af[2][4], bg[2][4];
    #pragma unroll
    for (int ks = 0; ks < 2; ++ks){
      #pragma unroll
      for (int f = 0; f < 4; ++f){
        int rr = wr * 64 + f * 16 + (lane & 15);
        int kB = ks * 64 + ((lane >> 4) << 4);
        af[ks][f] = *(const bf16x8*)(As + rr * 128 + (kB ^ ((rr & 7) << 4)));
        int rb = wc * 64 + f * 16 + (lane & 15);
        bg[ks][f] = *(const bf16x8*)(Bs + rb * 128 + (kB ^ ((rb & 7) << 4)));
      }
    }
    __syncthreads();                 // frag reads landed; LDS free
    if (kb + 1 < nk) STAGE(kb + 1);  // async prefetch while MFMAs run
    #pragma unroll
    for (int ks = 0; ks < 2; ++ks)
      #pragma unroll
      for (int i = 0; i < 4; ++i)
        #pragma unroll
        for (int j = 0; j < 4; ++j)
          acc[i][j] = __builtin_amdgcn_mfma_f32_16x16x32_bf16(af[ks][i], bg[ks][j], acc[i][j], 0, 0, 0);
  }

  // ---- EP_LSTM: register-direct. acc[i][g][q] holds gate g (incl. base0 for
  //      FB) for h-col jh = nb*32+wc*16+jl, row b = mb*128+wr*64+i*16+qr*4+q.
  if constexpr (EP == EP_LSTM){
    const int jl = lane & 15;
    const int qr = lane >> 4;
    const int jh = nb * 32 + wc * 16 + jl;
    const long pbase = (long)nb * 128 + wc * 64 + jl;
    float addv[4], f0v[4], f1v[4];
    #pragma unroll
    for (int g = 0; g < 4; ++g){
      long p = pbase + g * 16;
      if constexpr (FB){
        addv[g] = a.temb[(long)m * a.temb_ms + p];
        f0v[g]  = a.feff[(long)m * a.feff_ms + p];
        f1v[g]  = a.feff[(long)m * a.feff_ms + 2048 + p];
      } else {
        addv[g] = a.biasf[(long)m * a.bias_ms + p];
      }
    }
    // per-row pv table in LDS (aliases dead staging buffer)
    float* pvs = (float*)smem;   // [128][2]
    if constexpr (FB){
      if (tid < 128){
        float pv0 = 0.f, pv1 = 0.f;
        long b = mb * 128 + tid;
        if (a.tprev >= 0){
          const float* pp = a.prevp + ((long)m * 2048 + b) * 8;
          f32x4 pa = *(const f32x4*)(pp);
          f32x4 pb = *(const f32x4*)(pp + 4);
          pv0 = pa[0] + pa[2] + pb[0] + pb[2] + a.ob2[m * 2];
          pv1 = pa[1] + pa[3] + pb[1] + pb[3] + a.ob2[m * 2 + 1];
        }
        pvs[tid * 2]     = pv0;
        pvs[tid * 2 + 1] = pv1;
        if (nb == 0 && a.tprev >= 1){
          a.out_f[b * 960 + m * 160 + a.tprev * 2 + 0] = pv0;
          a.out_f[b * 960 + m * 160 + a.tprev * 2 + 1] = pv1;
        }
      }
      __syncthreads();
    }
    float* cb = a.cbuf + (long)m * a.c_ms + jh;
    bf16*  hb = a.hout + (long)m * a.h_ms + jh;
    #pragma unroll
    for (int i = 0; i < 4; ++i){
      #pragma unroll
      for (int q = 0; q < 4; ++q){
        int r = wr * 64 + i * 16 + qr * 4 + q;
        int b = mb * 128 + r;
        float pv0 = 0.f, pv1 = 0.f;
        if constexpr (FB){ pv0 = pvs[r * 2]; pv1 = pvs[r * 2 + 1]; }
        float g4[4];
        #pragma unroll
        for (int g = 0; g < 4; ++g){
          float v = acc[i][g][q] + addv[g];
          if constexpr (FB) v += pv0 * f0v[g] + pv1 * f1v[g];
          g4[g] = v;
        }
        long ro = (long)b * HD;
        float ci = sigmoidf_(g4[0]), cf = sigmoidf_(g4[1]);
        float cg = tanhf_(g4[2]),    co = sigmoidf_(g4[3]);
        float cn = cf * cb[ro] + ci * cg;
        cb[ro] = cn;
        hb[ro] = (bf16)(co * tanhf_(cn));
      }
    }
    return;
  }

  // ---- EP_OUT: fused out-projection, straight from registers ----
  if constexpr (EP == EP_OUT){
    __syncthreads();
    float* ps = (float*)smem;   // [128][4]: (row, wc*2+o)
    int colbase = wc * 64 + (lane & 15);
    float bv[4], w0v[4], w1v[4];
    #pragma unroll
    for (int j = 0; j < 4; ++j){
      int p = nb * 128 + colbase + j * 16;
      bv[j]  = a.biasf[(long)m * a.bias_ms + p];
      w0v[j] = a.w2[(long)m * 1024 + p];
      w1v[j] = a.w2[(long)m * 1024 + 512 + p];
    }
    #pragma unroll
    for (int i = 0; i < 4; ++i)
      #pragma unroll
      for (int q = 0; q < 4; ++q){
        float s0 = 0.f, s1 = 0.f;
        #pragma unroll
        for (int j = 0; j < 4; ++j){
          float v = fmaxf(acc[i][j][q] + bv[j], 0.0f);
          s0 += v * w0v[j]; s1 += v * w1v[j];
        }
        #pragma unroll
        for (int o2 = 1; o2 < 16; o2 <<= 1){ s0 += __shfl_xor(s0, o2); s1 += __shfl_xor(s1, o2); }
        if ((lane & 15) == 0){
          int row = wr * 64 + i * 16 + ((lane >> 4) << 2) + q;
          ps[row * 4 + wc * 2 + 0] = s0;
          ps[row * 4 + wc * 2 + 1] = s1;
        }
      }
    __syncthreads();
    if (tid < 128){
      int b = mb * 128 + tid;
      float o0 = ps[tid * 4 + 0] + ps[tid * 4 + 2];
      float o1 = ps[tid * 4 + 1] + ps[tid * 4 + 3];
      a.part[((long)m * 2048 + b) * 8 + nb * 2 + 0] = o0;
      a.part[((long)m * 2048 + b) * 8 + nb * 2 + 1] = o1;
    }
    return;
  }

  // ---- generic epilogues via LDS G tile, two 64-col passes (precompute only)
  #pragma unroll 1
  for (int ph = 0; ph < 2; ++ph){
    __syncthreads();
    if (wc == ph){
      #pragma unroll
      for (int i = 0; i < 4; ++i)
        #pragma unroll
        for (int j = 0; j < 4; ++j)
          #pragma unroll
          for (int q = 0; q < 4; ++q){
            int rr = wr * 64 + i * 16 + ((lane >> 4) << 2) + q;
            int cc = j * 16 + (lane & 15);
            Gf[rr * 66 + cc] = acc[i][j][q];
          }
    }
    __syncthreads();

    #pragma unroll 1
    for (int it = 0; it < 4; ++it){
      int u = it * 256 + tid;
      int r = u >> 3, cg = u & 7;
      int b = mb * 128 + r;
      int p0 = nb * 128 + ph * 64 + cg * 8;
      float v[8];
      #pragma unroll
      for (int k2 = 0; k2 < 8; ++k2){
        v[k2] = Gf[r * 66 + cg * 8 + k2];
        if (a.biasf) v[k2] += a.biasf[(long)m * a.bias_ms + p0 + k2];
        if constexpr (EP == EP_RELU) v[k2] = fmaxf(v[k2], 0.0f);
      }
      if constexpr (EP == EP_F32){
        float* dst = a.out_f + (long)m * a.outf_ms + (long)b * a.out_ld + p0;
        #pragma unroll
        for (int k2 = 0; k2 < 8; ++k2) dst[k2] = v[k2];
      } else if constexpr (EP == EP_INIT){
        if (p0 < HD){
          bf16x8 ov;
          #pragma unroll
          for (int k2 = 0; k2 < 8; ++k2) ov[k2] = (bf16)v[k2];
          *(bf16x8*)(a.hout  + (long)m * a.h_ms + (long)b * HD + p0) = ov;
          *(bf16x8*)(a.hout2 + (long)m * a.h_ms + (long)b * HD + p0) = ov;
        } else {
          int p1 = p0 - HD;
          float* d1 = a.cbuf  + (long)m * a.c_ms + (long)b * HD + p1;
          float* d2 = a.cbuf2 + (long)m * a.c_ms + (long)b * HD + p1;
          #pragma unroll
          for (int k2 = 0; k2 < 8; ++k2){ d1[k2] = v[k2]; d2[k2] = v[k2]; }
        }
      } else {
        bf16x8 ov;
        #pragma unroll
        for (int k2 = 0; k2 < 8; ++k2) ov[k2] = (bf16)v[k2];
        *(bf16x8*)(a.out_bf + (long)m * a.out_ms + (long)b * a.out_ld + p0) = ov;
      }
    }
  }
}

// ---------------------------------------------------------------------------
extern "C" void kernel_launch(void* const* d_in, const int* in_sizes, int n_in,
                              void* d_out, int out_size, void* d_ws, size_t ws_size,
                              hipStream_t stream)
{
  (void)in_sizes; (void)n_in; (void)out_size;
  const float* X     = (const float*)d_in[0];
  const float* mdW1  = (const float*)d_in[1];
  const float* mdb1  = (const float*)d_in[2];
  const float* mdW2  = (const float*)d_in[3];
  const float* mdb2  = (const float*)d_in[4];
  const float* mdW3  = (const float*)d_in[5];
  const float* mdb3  = (const float*)d_in[6];
  const float* ihW   = (const float*)d_in[7];
  const float* ihb   = (const float*)d_in[8];
  const float* tpW1  = (const float*)d_in[9];
  const float* tpb1  = (const float*)d_in[10];
  const float* tpW2  = (const float*)d_in[11];
  const float* tpb2  = (const float*)d_in[12];
  const float* fbW   = (const float*)d_in[13];
  const float* fbb   = (const float*)d_in[14];
  const float* l0Wih = (const float*)d_in[15];
  const float* l0bih = (const float*)d_in[16];
  const float* l0Whh = (const float*)d_in[17];
  const float* l0bhh = (const float*)d_in[18];
  const float* l1Wih = (const float*)d_in[19];
  const float* l1bih = (const float*)d_in[20];
  const float* l1Whh = (const float*)d_in[21];
  const float* l1bhh = (const float*)d_in[22];
  const float* opW1  = (const float*)d_in[23];
  const float* opb1  = (const float*)d_in[24];
  const float* opW2  = (const float*)d_in[25];
  const float* opb2  = (const float*)d_in[26];
  const float* cfW1  = (const float*)d_in[27];
  const float* cfb1  = (const float*)d_in[28];
  const float* cfW2  = (const float*)d_in[29];
  const float* cfb2  = (const float*)d_in[30];
  float* out = (float*)d_out;

  // ---- static arena (liveness-aliased). Total = 211,009,536 B ----
  const size_t NEED = 211009536;
  if (ws_size < NEED){
    k_diag<<<1, 64, 0, stream>>>(out, (float)(ws_size >> 20));
    return;
  }
  char* ws = (char*)d_ws;
  const long BH = (long)BATCH * HD;

  // persistent (loop-live)
  bf16*  Wp0     = (bf16*) (ws + 0);           // 12,582,912
  bf16*  Wp1     = (bf16*) (ws + 12582912);    // 25,165,824
  bf16*  WpO     = (bf16*) (ws + 37748736);    //  3,145,728
  bf16*  base0p  = (bf16*) (ws + 40894464);    // 50,331,648
  float* tembW0p = (float*)(ws + 91226112);    //  6,291,456
  float* bias1p  = (float*)(ws + 97517568);    //     49,152
  float* Feffp   = (float*)(ws + 97566720);    //     98,304
  char*  REG     =          ws + 97763328;     // 100,663,296 (h0|h1|c0|c1)
  bf16*  h0b     = (bf16*) (REG + 0);
  bf16*  h1b     = (bf16*) (REG + 25165824);
  float* c0      = (float*)(REG + 50331648);
  float* c1      = (float*)(REG + 75497472);
  char*  MREG    =          ws + 198426624;    // 12,582,912

  // precompute temporaries inside REG (dead before EP_INIT writes h/c)
  bf16*  W0ip    = (bf16*) (REG + 0);
  bf16*  mdW1p   = (bf16*) (REG + 12582912);
  bf16*  mdW2p   = (bf16*) (REG + 18874368);
  bf16*  mdW3p   = (bf16*) (REG + 25165824);
  bf16*  tembb   = (bf16*) (REG + 28311552);
  float* bias0p  = (float*)(REG + 28442624);
  bf16*  lt1     = (bf16*) (REG + 28491776);
  bf16*  t1buf   = (bf16*) (REG + 29540352);
  bf16*  t2buf   = (bf16*) (REG + 54706176);
  bf16*  mfbuf   = (bf16*) (REG + 67289088);
  // MREG: precompute temporaries + loop-live part buffer (disjoint)
  bf16*  xb      = (bf16*) (MREG + 0);         //  2,097,152
  bf16*  ihWp    = (bf16*) (MREG + 2097152);   //  6,291,456
  bf16*  cfW1p   = (bf16*) (MREG + 8388608);   //    262,144
  float* part    = (float*)(MREG + 8650752);   //    393,216  [m][b][4][2]

  // ---- pack / convert ----
  k_pack<false,false><<<dim3(512),  256, 0, stream>>>(xb,    X,     nullptr, 512,  2048, 512);
  k_pack<true ,false><<<dim3(3072), 256, 0, stream>>>(Wp0,   l0Whh, nullptr, 512,  2048, 512);
  k_pack<true ,false><<<dim3(3072), 256, 0, stream>>>(W0ip,  l0Wih, nullptr, 512,  2048, 512);
  k_pack<true ,true ><<<dim3(6144), 256, 0, stream>>>(Wp1,   l1Wih, l1Whh,   1024, 2048, 512);
  k_pack<false,false><<<dim3(768),  256, 0, stream>>>(WpO,   opW1,  nullptr, 512,  512,  512);
  k_pack<false,false><<<dim3(1536), 256, 0, stream>>>(mdW1p, mdW1,  nullptr, 512,  1024, 512);
  k_pack<false,false><<<dim3(1536), 256, 0, stream>>>(mdW2p, mdW2,  nullptr, 1024, 512,  1024);
  k_pack<false,false><<<dim3(768),  256, 0, stream>>>(mdW3p, mdW3,  nullptr, 512,  512,  512);
  k_pack<false,false><<<dim3(1536), 256, 0, stream>>>(ihWp,  ihW,   nullptr, 512,  1024, 512);
  k_pack<false,false><<<dim3(64),   256, 0, stream>>>(cfW1p, cfW1,  nullptr, 512,  256,  512);

  k_temb  <<<dim3(128), 256, 0, stream>>>(tembb, tpW1, tpb1, tpW2, tpb2);
  k_biases<<<dim3(48),  256, 0, stream>>>(bias0p, bias1p, l0bih, l0bhh, l1bih, l1bhh, l0Wih, fbb);
  k_feffp <<<dim3(96),  256, 0, stream>>>(Feffp, fbW, l0Wih);
  k_zero  <<<dim3(384), 256, 0, stream>>>(part, out);

  // ---- precompute GEMMs (order matters for arena aliasing) ----
  { GArgs g{}; g.A1 = xb; g.a1_ms = 0; g.a_ld = 512; g.Bw = mdW1p; g.b_ms = (long)1024*512;
    g.K = 512; g.ksplit = 512; g.NBt = 8; g.MBt = 16; g.biasf = mdb1; g.bias_ms = 1024;
    g.out_bf = t1buf; g.out_ms = (long)2048*1024; g.out_ld = 1024;
    gemm_k<EP_RELU,false,false><<<dim3(16*8*6), 256, 0, stream>>>(g); }
  { GArgs g{}; g.A1 = t1buf; g.a1_ms = (long)2048*1024; g.a_ld = 1024; g.Bw = mdW2p; g.b_ms = (long)512*1024;
    g.K = 1024; g.ksplit = 1024; g.NBt = 4; g.MBt = 16; g.biasf = mdb2; g.bias_ms = 512;
    g.out_bf = t2buf; g.out_ms = BH; g.out_ld = 512;
    gemm_k<EP_RELU,false,false><<<dim3(16*4*6), 256, 0, stream>>>(g); }
  { GArgs g{}; g.A1 = t2buf; g.a1_ms = BH; g.a_ld = 512; g.Bw = mdW3p; g.b_ms = (long)512*512;
    g.K = 512; g.ksplit = 512; g.NBt = 4; g.MBt = 16; g.biasf = mdb3; g.bias_ms = 512;
    g.out_bf = mfbuf; g.out_ms = BH; g.out_ld = 512;
    gemm_k<EP_BF16,false,false><<<dim3(16*4*6), 256, 0, stream>>>(g); }
  { GArgs g{}; g.A1 = tembb; g.a1_ms = 0; g.a_ld = 512; g.Bw = W0ip; g.b_ms = (long)2048*512;
    g.K = 512; g.ksplit = 512; g.NBt = 16; g.MBt = 1; g.biasf = nullptr;
    g.out_f = tembW0p; g.outf_ms = (long)128*2048; g.out_ld = 2048;
    gemm_k<EP_F32,false,false><<<dim3(1*16*6), 256, 0, stream>>>(g); }
  // base0 = mf @ W0i.T + bias0p
  { GArgs g{}; g.A1 = mfbuf; g.a1_ms = BH; g.a_ld = 512; g.Bw = W0ip; g.b_ms = (long)2048*512;
    g.K = 512; g.ksplit = 512; g.NBt = 16; g.MBt = 16; g.biasf = bias0p; g.bias_ms = 2048;
    g.out_bf = base0p; g.out_ms = (long)2048*2048; g.out_ld = 2048;
    gemm_k<EP_BF16,false,false><<<dim3(16*16*6), 256, 0, stream>>>(g); }
  { GArgs g{}; g.A1 = xb; g.a1_ms = 0; g.a_ld = 512; g.Bw = cfW1p; g.b_ms = 0;
    g.K = 512; g.ksplit = 512; g.NBt = 2; g.MBt = 16; g.biasf = cfb1; g.bias_ms = 0;
    g.out_bf = lt1; g.out_ms = 0; g.out_ld = 256;
    gemm_k<EP_RELU,false,false><<<dim3(16*2*1), 256, 0, stream>>>(g); }
  k_logits<<<dim3(8), 256, 0, stream>>>(lt1, cfW2, cfb2, out + 1966080, out + 1966080 + 12288);
  { GArgs g{}; g.A1 = xb; g.a1_ms = 0; g.a_ld = 512; g.Bw = ihWp; g.b_ms = (long)1024*512;
    g.K = 512; g.ksplit = 512; g.NBt = 8; g.MBt = 16; g.biasf = ihb; g.bias_ms = 1024;
    g.hout = h0b; g.h_ms = BH; g.hout2 = h1b; g.cbuf = c0; g.c_ms = BH; g.cbuf2 = c1;
    gemm_k<EP_INIT,false,false><<<dim3(16*8*6), 256, 0, stream>>>(g); }

  // ---- recurrent loop (3 dispatches/step) ----
  for (int t = 0; t < 80; ++t){
    int cur = t & 1, nxt = cur ^ 1;
    { GArgs g{}; g.A1 = h0b + (size_t)cur * 6 * BH; g.a1_ms = BH; g.a_ld = 512;
      g.Bw = Wp0; g.b_ms = (long)2048*512; g.K = 512; g.ksplit = 512; g.NBt = 16; g.MBt = 16;
      g.tprev = t - 1;
      g.baseb = base0p; g.baseb_ms = (long)2048*2048;
      g.temb = tembW0p + (long)t * 2048; g.temb_ms = (long)128*2048;
      g.feff = Feffp; g.feff_ms = 4096;
      g.prevp = part; g.ob2 = opb2; g.out_f = out;
      g.cbuf = c0; g.c_ms = BH;
      g.hout = h0b + (size_t)nxt * 6 * BH; g.h_ms = BH;
      gemm_k<EP_LSTM,false,true><<<dim3(16*16*6), 256, 0, stream>>>(g); }
    { GArgs g{}; g.A1 = h0b + (size_t)nxt * 6 * BH; g.A2 = h1b + (size_t)cur * 6 * BH;
      g.a1_ms = BH; g.a2_ms = BH; g.a_ld = 512;
      g.Bw = Wp1; g.b_ms = (long)2048*1024; g.K = 1024; g.ksplit = 512; g.NBt = 16; g.MBt = 16;
      g.biasf = bias1p; g.bias_ms = 2048;
      g.cbuf = c1; g.c_ms = BH;
      g.hout = h1b + (size_t)nxt * 6 * BH; g.h_ms = BH;
      gemm_k<EP_LSTM,true,false><<<dim3(16*16*6), 256, 0, stream>>>(g); }
    { GArgs g{}; g.A1 = h1b + (size_t)nxt * 6 * BH; g.a1_ms = BH; g.a_ld = 512;
      g.Bw = WpO; g.b_ms = (long)512*512; g.K = 512; g.ksplit = 512; g.NBt = 4; g.MBt = 16;
      g.biasf = opb1; g.bias_ms = 512;
      g.w2 = opW2; g.part = part;
      gemm_k<EP_OUT,false,false><<<dim3(16*4*6), 256, 0, stream>>>(g); }
  }
  k_red<<<dim3(48), 256, 0, stream>>>(part, opb2, out);
}